// Round 13
// baseline (15516.466 us; speedup 1.0000x reference)
//
#include <hip/hip_runtime.h>

typedef __bf16 bf16;
typedef __bf16 bf16x8 __attribute__((ext_vector_type(8)));
typedef __bf16 bf16x4 __attribute__((ext_vector_type(4)));
typedef float  f32x4  __attribute__((ext_vector_type(4)));

#define T_LEN 70
#define BATCH 64
#define HDIM  1024
#define GDIM  4096
#define VOCAB 32000
#define TBROW (T_LEN * BATCH)   // 4480

#define MFMA16(a, b, c) __builtin_amdgcn_mfma_f32_16x16x32_bf16((a), (b), (c), 0, 0, 0)

typedef const __attribute__((address_space(1))) void gas_void;
typedef __attribute__((address_space(3))) void las_void;

// ---------------------------------------------------------------------------
__global__ void split_kernel(const float* __restrict__ w, bf16* __restrict__ hi,
                             bf16* __restrict__ lo, int n4) {
    int stride = gridDim.x * blockDim.x;
    for (int i = blockIdx.x * blockDim.x + threadIdx.x; i < n4; i += stride) {
        float4 v = reinterpret_cast<const float4*>(w)[i];
        bf16 h0 = (bf16)v.x, h1 = (bf16)v.y, h2 = (bf16)v.z, h3 = (bf16)v.w;
        bf16x4 hv = {h0, h1, h2, h3};
        bf16x4 lv = {(bf16)(v.x - (float)h0), (bf16)(v.y - (float)h1),
                     (bf16)(v.z - (float)h2), (bf16)(v.w - (float)h3)};
        reinterpret_cast<bf16x4*>(hi)[i] = hv;
        reinterpret_cast<bf16x4*>(lo)[i] = lv;
    }
}

__global__ void conv_kernel(const float* __restrict__ w, bf16* __restrict__ hi, int n4) {
    int stride = gridDim.x * blockDim.x;
    for (int i = blockIdx.x * blockDim.x + threadIdx.x; i < n4; i += stride) {
        float4 v = reinterpret_cast<const float4*>(w)[i];
        bf16x4 hv = {(bf16)v.x, (bf16)v.y, (bf16)v.z, (bf16)v.w};
        reinterpret_cast<bf16x4*>(hi)[i] = hv;
    }
}

__global__ void embed_kernel(const int* __restrict__ x, const float* __restrict__ emb,
                             bf16* __restrict__ xh, bf16* __restrict__ xl) {
    int row = blockIdx.x;
    int tok = x[row];
    const float4* src = reinterpret_cast<const float4*>(emb + (size_t)tok * HDIM);
    bf16x4* dh = reinterpret_cast<bf16x4*>(xh + (size_t)row * HDIM);
    bf16x4* dl = reinterpret_cast<bf16x4*>(xl + (size_t)row * HDIM);
    for (int i = threadIdx.x; i < HDIM / 4; i += blockDim.x) {
        float4 v = src[i];
        bf16 h0 = (bf16)v.x, h1 = (bf16)v.y, h2 = (bf16)v.z, h3 = (bf16)v.w;
        dh[i] = (bf16x4){h0, h1, h2, h3};
        dl[i] = (bf16x4){(bf16)(v.x - (float)h0), (bf16)(v.y - (float)h1),
                         (bf16)(v.z - (float)h2), (bf16)(v.w - (float)h3)};
    }
}

// initial h stored at parity 1 (first reads occur at input-parity 1)
__global__ void init_kernel(const float* __restrict__ h0, const float* __restrict__ c0,
                            bf16* __restrict__ hsb, float* __restrict__ cst) {
    int i = blockIdx.x * blockDim.x + threadIdx.x;
    int l = i >> 16, r = i & 65535;
    float v = h0[i];
    bf16 h = (bf16)v;
    hsb[(size_t)((l * 2 + 1) * 2 + 0) * 65536 + r] = h;
    hsb[(size_t)((l * 2 + 1) * 2 + 1) * 65536 + r] = (bf16)(v - (float)h);
    cst[i] = c0[i];
}

// ---------------------------------------------------------------------------
// GEMM C = sum_p A_p B_p^T + bias (unchanged from r7)
// ---------------------------------------------------------------------------
__global__ __launch_bounds__(256) void gemm_bt(
    const bf16* __restrict__ a0, const bf16* __restrict__ a1, const bf16* __restrict__ a2,
    const bf16* __restrict__ b0, const bf16* __restrict__ b1, const bf16* __restrict__ b2,
    int npass, int K, const float* __restrict__ bias, float* __restrict__ C, int ldc) {
    __shared__ __align__(16) char As[128 * 128];
    __shared__ __align__(16) char Bs[128 * 128];
    const int tid = threadIdx.x;
    const int wid = tid >> 6, lane = tid & 63;
    const int l15 = lane & 15, l4 = lane >> 4;

    const int nbx = gridDim.x, mt = gridDim.y, nwg = nbx * mt;
    const int flat = blockIdx.y * nbx + blockIdx.x;
    const int xcd = flat & 7, o8 = flat >> 3;
    const int q8 = nwg >> 3, r8 = nwg & 7;
    const int wg = (xcd < r8 ? xcd * (q8 + 1) : r8 * (q8 + 1) + (xcd - r8) * q8) + o8;
    const int m0 = (wg % mt) * 128, n0 = (wg / mt) * 128;

    const int wr = (wid >> 1) * 64, wc = (wid & 1) * 64;
    const int swz_rd = (l15 & 7) << 4;
    const int rowL = lane >> 3;
    const int colE = (((lane & 7) ^ rowL)) << 3;

    f32x4 acc[4][4];
#pragma unroll
    for (int i = 0; i < 4; ++i)
#pragma unroll
        for (int j = 0; j < 4; ++j) acc[i][j] = (f32x4){0.f, 0.f, 0.f, 0.f};

    for (int p = 0; p < npass; ++p) {
        const bf16* A = (p == 0) ? a0 : ((p == 1) ? a1 : a2);
        const bf16* B = (p == 0) ? b0 : ((p == 1) ? b1 : b2);
        for (int k0 = 0; k0 < K; k0 += 64) {
            __syncthreads();
#pragma unroll
            for (int c2 = 0; c2 < 4; ++c2) {
                const int ch = wid * 4 + c2;
                const int row = ch * 8 + rowL;
                __builtin_amdgcn_global_load_lds(
                    (gas_void*)(A + (size_t)(m0 + row) * K + k0 + colE),
                    (las_void*)(As + ch * 1024), 16, 0, 0);
                __builtin_amdgcn_global_load_lds(
                    (gas_void*)(B + (size_t)(n0 + row) * K + k0 + colE),
                    (las_void*)(Bs + ch * 1024), 16, 0, 0);
            }
            __syncthreads();
#pragma unroll
            for (int ks = 0; ks < 2; ++ks) {
                const int cb = (ks * 64 + l4 * 16) ^ swz_rd;
                bf16x8 af[4], bfr[4];
#pragma unroll
                for (int mi = 0; mi < 4; ++mi)
                    af[mi] = *reinterpret_cast<const bf16x8*>(As + (wr + mi * 16 + l15) * 128 + cb);
#pragma unroll
                for (int ni = 0; ni < 4; ++ni)
                    bfr[ni] = *reinterpret_cast<const bf16x8*>(Bs + (wc + ni * 16 + l15) * 128 + cb);
#pragma unroll
                for (int mi = 0; mi < 4; ++mi)
#pragma unroll
                    for (int ni = 0; ni < 4; ++ni)
                        acc[mi][ni] = MFMA16(af[mi], bfr[ni], acc[mi][ni]);
            }
        }
    }
#pragma unroll
    for (int ni = 0; ni < 4; ++ni) {
        const int col = n0 + wc + ni * 16 + l15;
        const float bv = bias[col];
#pragma unroll
        for (int mi = 0; mi < 4; ++mi) {
            const int row0 = m0 + wr + mi * 16 + l4 * 4;
#pragma unroll
            for (int r = 0; r < 4; ++r)
                C[(size_t)(row0 + r) * ldc + col] = acc[mi][ni][r] + bv;
        }
    }
}

// ---------------------------------------------------------------------------
// Wavefront LSTM v9: 512 blocks (8 gate-cols each) -> 2 blocks/CU for TLP.
// Chunk = 64 rows x 64 k: A hi+lo 16KB + B 4KB (packed: MFMA's 16 N-slots =
// 2 matrices x 8 cols -> one MFMA triple serves both matrices). Double-buffer,
// distance-1 prefetch, counted vmcnt(3/2). Per-group register accumulation,
// one LDS-atomic reduce per group into R0/R1/R2; single-region gates.
// LDS: 2 x 20480 bufs + R0/R1/R2 (2KB each) = 47104 B -> 2 blocks/CU.
// ---------------------------------------------------------------------------
__global__ __launch_bounds__(512, 4) void lstm_wave(
    const float* __restrict__ cin,
    const bf16* __restrict__ Wh0h, const bf16* __restrict__ Wh0l,
    const bf16* __restrict__ Wi1h, const bf16* __restrict__ Wi1l,
    const bf16* __restrict__ Wh1h, const bf16* __restrict__ Wh1l,
    const bf16* __restrict__ Wi2h, const bf16* __restrict__ Wi2l,
    const bf16* __restrict__ Wh2h, const bf16* __restrict__ Wh2l,
    const float* __restrict__ px0,
    const float* __restrict__ bh0, const float* __restrict__ bi1,
    const float* __restrict__ bh1, const float* __restrict__ bi2,
    const float* __restrict__ bh2,
    bf16* __restrict__ hsb, bf16* __restrict__ outh, int* __restrict__ bar,
    bf16* __restrict__ dump) {
    __shared__ __align__(16) char smem[47104];

    const int tid = threadIdx.x;
    const int lane = tid & 63, w = tid >> 6;
    const int l15 = lane & 15, l4 = lane >> 4;
    const int wm = w & 3, wn = w >> 2;
    const int j0 = blockIdx.x * 2;               // 2 h-cols per block

    // A staging: wave w stages rows [w*8, w*8+8); lane: row+=l>>3, piece l&7
    const size_t aoff = (size_t)(w * 8 + (lane >> 3)) * HDIM +
                        (size_t)(((lane & 7) ^ (lane >> 3)) * 8);
    // B staging (waves 0-3): hl=w>>1, mat=w&1; lane: col_local=l>>3, piece l&7
    const size_t boff = (size_t)((lane >> 4) * 1024 + j0 + ((lane >> 3) & 1)) * HDIM +
                        (size_t)(((lane & 7) ^ (lane >> 3)) * 8);
    const int bdst = 16384 + (w >> 1) * 2048 + (w & 1) * 1024;
    // gates: 128 threads, (batch b, within wi)
    const int gb = tid >> 1, gwi = tid & 1;

    float creg0 = 0.f, creg1 = 0.f, creg2 = 0.f;
    if (tid < 128) {
        creg0 = cin[0 * 65536 + gb * 1024 + j0 + gwi];
        creg1 = cin[1 * 65536 + gb * 1024 + j0 + gwi];
        creg2 = cin[2 * 65536 + gb * 1024 + j0 + gwi];
    }
    for (int i = tid; i < 1536; i += 512)
        reinterpret_cast<float*>(smem + 40960)[i] = 0.f;
    asm volatile("s_waitcnt vmcnt(0) lgkmcnt(0)" ::: "memory");
    __syncthreads();

    auto hsp = [&](int l, int par, int hl) {
        return hsb + (((size_t)l * 2 + par) * 2 + hl) * 65536;
    };

    int barid = 0;
    f32x4 acc = (f32x4){0.f, 0.f, 0.f, 0.f};

    auto COMPUTE = [&](int buf) {
        const char* base = smem + buf * 20480;
        const int kx = wn * 64 + l4 * 16;
        const int sz = (l15 & 7) << 4;
        const int co = kx ^ sz;
        const int arow = wm * 16 + l15;
        bf16x8 ah = *reinterpret_cast<const bf16x8*>(base + arow * 128 + co);
        bf16x8 al = *reinterpret_cast<const bf16x8*>(base + 8192 + arow * 128 + co);
        const char* bb = base + 16384;
        bf16x8 wh = *reinterpret_cast<const bf16x8*>(bb + l15 * 128 + co);
        bf16x8 wl = *reinterpret_cast<const bf16x8*>(bb + 2048 + l15 * 128 + co);
        acc = MFMA16(ah, wh, acc);
        acc = MFMA16(ah, wl, acc);
        acc = MFMA16(al, wh, acc);
    };

    auto ATOMADD = [&](int g) {
        const int RA = (g == 0) ? 0 : (g == 1) ? 2048 : 4096;
        const int RB = (g == 0) ? 2048 : 4096;
        const bool hasB = (g < 2);
        const int mat = l15 >> 3, cl = l15 & 7;
        if (!mat || hasB) {
            float* Rt = reinterpret_cast<float*>(smem + 40960 + (mat ? RB : RA));
#pragma unroll
            for (int r = 0; r < 4; ++r)
                atomicAdd(&Rt[(wm * 16 + l4 * 4 + r) * 8 + cl], acc[r]);
        }
        acc = (f32x4){0.f, 0.f, 0.f, 0.f};
    };

    auto GATE = [&](int Roff, const float* bia, const float* bib, bool usepx, int sr,
                    bool act, bf16* HH, bf16* HL, bf16* OH, float& CREG) {
        asm volatile("s_waitcnt lgkmcnt(0)" ::: "memory");
        __builtin_amdgcn_s_barrier();
        __builtin_amdgcn_sched_barrier(0);
        if (tid < 128) {
            float* R = reinterpret_cast<float*>(smem + 40960 + Roff);
            float p[4];
#pragma unroll
            for (int q = 0; q < 4; ++q) {
                p[q] = R[gb * 8 + q * 2 + gwi] + bia[q * 1024 + j0 + gwi];
                if (bib) p[q] += bib[q * 1024 + j0 + gwi];
                if (usepx) p[q] += px0[(size_t)sr * 262144 + (size_t)gb * 4096 +
                                       q * 1024 + j0 + gwi];
            }
            const float ig = 1.f / (1.f + expf(-p[0]));
            const float fg = 1.f / (1.f + expf(-p[1]));
            const float og = 1.f / (1.f + expf(-p[2]));
            const float gg = tanhf(p[3]);
            const float c2v = fg * CREG + ig * gg;
            const float h2v = og * tanhf(c2v);
            if (act) CREG = c2v;
            const int idx = gb * 1024 + j0 + gwi;
            const bf16 hhi = (bf16)h2v;
            HH[idx] = hhi;
            HL[idx] = (bf16)(h2v - (float)hhi);
            OH[idx] = hhi;
#pragma unroll
            for (int q = 0; q < 4; ++q) R[gb * 8 + q * 2 + gwi] = 0.f;
        }
        asm volatile("s_waitcnt vmcnt(0) lgkmcnt(0)" ::: "memory");
        __builtin_amdgcn_s_barrier();
        __builtin_amdgcn_sched_barrier(0);
    };

#pragma unroll 1
    for (int s = 0; s < T_LEN + 2; ++s) {
        const int ps = s & 1;
        const bool act0 = (s < T_LEN);
        const bool act1 = (s >= 1) && (s <= T_LEN);
        const bool act2 = (s >= 2);
        const int sread = act0 ? s : 0;

        const bf16* A0h = hsp(0, 1 - ps, 0); const bf16* A0l = hsp(0, 1 - ps, 1);
        const bf16* A1h = hsp(1, ps, 0);     const bf16* A1l = hsp(1, ps, 1);
        const bf16* A2h = hsp(2, 1 - ps, 0); const bf16* A2l = hsp(2, 1 - ps, 1);
        bf16* dH0h = act0 ? hsp(0, ps, 0)     : dump;
        bf16* dH0l = act0 ? hsp(0, ps, 1)     : dump;
        bf16* dH1h = act1 ? hsp(1, 1 - ps, 0) : dump;
        bf16* dH1l = act1 ? hsp(1, 1 - ps, 1) : dump;
        bf16* dH2h = act2 ? hsp(2, ps, 0)     : dump;
        bf16* dH2l = act2 ? hsp(2, ps, 1)     : dump;
        bf16* ohp  = act2 ? (outh + (size_t)(s - 2) * 65536) : dump;

        auto ISSUE = [&](int c, int buf) {
            const int g = c >> 4;
            const size_t k0 = (size_t)((c & 15) * 64);
            char* base = smem + buf * 20480;
            const bf16* pah = (g == 0) ? A0h : (g == 1) ? A1h : A2h;
            const bf16* pal = (g == 0) ? A0l : (g == 1) ? A1l : A2l;
            __builtin_amdgcn_global_load_lds((gas_void*)(pah + aoff + k0),
                                             (las_void*)(base + w * 1024), 16, 0, 0);
            __builtin_amdgcn_global_load_lds((gas_void*)(pal + aoff + k0),
                                             (las_void*)(base + 8192 + w * 1024), 16, 0, 0);
            if (w < 4) {
                const bf16* pb;
                if ((w & 1) == 0)
                    pb = (w >> 1) ? ((g == 0) ? Wh0l : (g == 1) ? Wh1l : Wh2l)
                                  : ((g == 0) ? Wh0h : (g == 1) ? Wh1h : Wh2h);
                else
                    pb = (w >> 1) ? ((g == 0) ? Wi1l : (g == 1) ? Wi2l : Wh2l)
                                  : ((g == 0) ? Wi1h : (g == 1) ? Wi2h : Wh2h);
                __builtin_amdgcn_global_load_lds((gas_void*)(pb + boff + k0),
                                                 (las_void*)(base + bdst), 16, 0, 0);
            }
        };

        ISSUE(0, 0);
#pragma unroll 1
        for (int i = 0; i < 48; ++i) {
            if (i < 47) {
                ISSUE(i + 1, (i + 1) & 1);
                if (w < 4) asm volatile("s_waitcnt vmcnt(3)" ::: "memory");
                else       asm volatile("s_waitcnt vmcnt(2)" ::: "memory");
            } else {
                asm volatile("s_waitcnt vmcnt(0)" ::: "memory");
            }
            __builtin_amdgcn_s_barrier();
            __builtin_amdgcn_sched_barrier(0);
            COMPUTE(i & 1);
            asm volatile("s_waitcnt lgkmcnt(0)" ::: "memory");
            __builtin_amdgcn_s_barrier();
            __builtin_amdgcn_sched_barrier(0);
            if ((i & 15) == 15) {
                const int g = i >> 4;
                ATOMADD(g);
                if (g == 0)
                    GATE(0, bh0, (const float*)nullptr, true, sread, act0,
                         dH0h, dH0l, dump, creg0);
                else if (g == 1)
                    GATE(2048, bi1, bh1, false, 0, act1, dH1h, dH1l, dump, creg1);
                else
                    GATE(4096, bi2, bh2, false, 0, act2, dH2h, dH2l, ohp, creg2);
            }
        }

        // ---- grid barrier ----
        if (s < T_LEN + 1) {
            if (tid == 0) {
                int* slot = bar + barid * 128 + (blockIdx.x & 7) * 16;
                __hip_atomic_fetch_add(slot, 1, __ATOMIC_RELEASE,
                                       __HIP_MEMORY_SCOPE_AGENT);
                for (;;) {
                    int sum = 0;
#pragma unroll
                    for (int k = 0; k < 8; ++k)
                        sum += __hip_atomic_load(bar + barid * 128 + k * 16,
                                                 __ATOMIC_RELAXED,
                                                 __HIP_MEMORY_SCOPE_AGENT);
                    if (sum >= (int)gridDim.x) break;
                    __builtin_amdgcn_s_sleep(2);
                }
                __builtin_amdgcn_fence(__ATOMIC_ACQUIRE, "agent");
            }
            ++barid;
            __builtin_amdgcn_s_barrier();
            __builtin_amdgcn_sched_barrier(0);
        }
    }
}

// ---------------------------------------------------------------------------
extern "C" void kernel_launch(void* const* d_in, const int* in_sizes, int n_in,
                              void* d_out, int out_size, void* d_ws, size_t ws_size,
                              hipStream_t stream) {
    (void)in_sizes; (void)n_in; (void)out_size; (void)ws_size;
    const int*   x   = (const int*)d_in[0];
    const float* h0  = (const float*)d_in[1];
    const float* c0  = (const float*)d_in[2];
    const float* emb = (const float*)d_in[3];
    const float* W[6] = { (const float*)d_in[4],  (const float*)d_in[6],
                          (const float*)d_in[8],  (const float*)d_in[10],
                          (const float*)d_in[12], (const float*)d_in[14] };
    const float* bi0 = (const float*)d_in[5];
    const float* bh0 = (const float*)d_in[7];
    const float* bi1 = (const float*)d_in[9];
    const float* bh1 = (const float*)d_in[11];
    const float* bi2 = (const float*)d_in[13];
    const float* bh2 = (const float*)d_in[15];
    const float* Wd  = (const float*)d_in[16];
    const float* bd  = (const float*)d_in[17];

    char* ws = (char*)d_ws;
    size_t off = 0;
    float* px0 = (float*)(ws + off); off += (size_t)TBROW * GDIM * 4;
    bf16* wsp[12];
    for (int i = 0; i < 12; ++i) { wsp[i] = (bf16*)(ws + off); off += (size_t)GDIM * HDIM * 2; }
    bf16* wdb  = (bf16*)(ws + off); off += (size_t)VOCAB * HDIM * 2;
    bf16* xeh  = (bf16*)(ws + off); off += (size_t)TBROW * HDIM * 2;
    bf16* xel  = (bf16*)(ws + off); off += (size_t)TBROW * HDIM * 2;
    bf16* outh = (bf16*)(ws + off); off += (size_t)TBROW * HDIM * 2;
    bf16* hsb  = (bf16*)(ws + off); off += (size_t)12 * BATCH * HDIM * 2;
    float* cst = (float*)(ws + off); off += (size_t)3 * BATCH * HDIM * 4;
    int*  bar  = (int*)(ws + off);  off += 72 * 128 * 4;
    bf16* dump = (bf16*)(ws + off); off += (size_t)BATCH * HDIM * 2;

    // wsp[0..1]=Wi0, [2..3]=Wh0, [4..5]=Wi1, [6..7]=Wh1, [8..9]=Wi2, [10..11]=Wh2
    for (int i = 0; i < 6; ++i)
        split_kernel<<<1024, 256, 0, stream>>>(W[i], wsp[2 * i], wsp[2 * i + 1],
                                               GDIM * HDIM / 4);
    conv_kernel<<<2048, 256, 0, stream>>>(Wd, wdb, VOCAB * HDIM / 4);
    embed_kernel<<<TBROW, 256, 0, stream>>>(x, emb, xeh, xel);
    init_kernel<<<768, 256, 0, stream>>>(h0, c0, hsb, cst);
    (void)hipMemsetAsync(bar, 0, 72 * 128 * 4, stream);

    // px0 = xe @ Wi0^T + bi0 (split-3)
    dim3 gpx(GDIM / 128, TBROW / 128);
    gemm_bt<<<gpx, 256, 0, stream>>>(xeh, xel, xeh, wsp[0], wsp[0], wsp[1],
                                     3, HDIM, bi0, px0, GDIM);

    // whole recurrence: 512 blocks, 2 blocks/CU for TLP
    lstm_wave<<<512, 512, 0, stream>>>(
        c0,
        wsp[2], wsp[3],           // Wh0
        wsp[4], wsp[5],           // Wi1
        wsp[6], wsp[7],           // Wh1
        wsp[8], wsp[9],           // Wi2
        wsp[10], wsp[11],         // Wh2
        px0, bh0, bi1, bh1, bi2, bh2,
        hsb, outh, bar, dump);

    // decoder: d_out = outh @ Wd^T + bd
    dim3 gdec(VOCAB / 128, TBROW / 128);
    gemm_bt<<<gdec, 256, 0, stream>>>(outh, nullptr, nullptr, wdb, nullptr, nullptr,
                                      1, HDIM, bd, (float*)d_out, VOCAB);
}

// Round 14
// 2492.414 us; speedup vs baseline: 6.2255x; 6.2255x over previous
//
#include <hip/hip_runtime.h>

typedef __bf16 bf16;
typedef __bf16 bf16x8 __attribute__((ext_vector_type(8)));
typedef __bf16 bf16x4 __attribute__((ext_vector_type(4)));
typedef float  f32x4  __attribute__((ext_vector_type(4)));
typedef _Float16 f16;
typedef _Float16 f16x8 __attribute__((ext_vector_type(8)));
typedef _Float16 f16x4v __attribute__((ext_vector_type(4)));

#define T_LEN 70
#define BATCH 64
#define HDIM  1024
#define GDIM  4096
#define VOCAB 32000
#define TBROW (T_LEN * BATCH)   // 4480

#define MFMA16(a, b, c) __builtin_amdgcn_mfma_f32_16x16x32_bf16((a), (b), (c), 0, 0, 0)
#define MFMAH(a, b, c)  __builtin_amdgcn_mfma_f32_16x16x32_f16((a), (b), (c), 0, 0, 0)

typedef const __attribute__((address_space(1))) void gas_void;
typedef __attribute__((address_space(3))) void las_void;

// ---------------------------------------------------------------------------
__global__ void split_kernel(const float* __restrict__ w, bf16* __restrict__ hi,
                             bf16* __restrict__ lo, int n4) {
    int stride = gridDim.x * blockDim.x;
    for (int i = blockIdx.x * blockDim.x + threadIdx.x; i < n4; i += stride) {
        float4 v = reinterpret_cast<const float4*>(w)[i];
        bf16 h0 = (bf16)v.x, h1 = (bf16)v.y, h2 = (bf16)v.z, h3 = (bf16)v.w;
        bf16x4 hv = {h0, h1, h2, h3};
        bf16x4 lv = {(bf16)(v.x - (float)h0), (bf16)(v.y - (float)h1),
                     (bf16)(v.z - (float)h2), (bf16)(v.w - (float)h3)};
        reinterpret_cast<bf16x4*>(hi)[i] = hv;
        reinterpret_cast<bf16x4*>(lo)[i] = lv;
    }
}

__global__ void conv_kernel(const float* __restrict__ w, bf16* __restrict__ hi, int n4) {
    int stride = gridDim.x * blockDim.x;
    for (int i = blockIdx.x * blockDim.x + threadIdx.x; i < n4; i += stride) {
        float4 v = reinterpret_cast<const float4*>(w)[i];
        bf16x4 hv = {(bf16)v.x, (bf16)v.y, (bf16)v.z, (bf16)v.w};
        reinterpret_cast<bf16x4*>(hi)[i] = hv;
    }
}

__global__ void conv16_kernel(const float* __restrict__ w, f16* __restrict__ dst, int n4) {
    int stride = gridDim.x * blockDim.x;
    for (int i = blockIdx.x * blockDim.x + threadIdx.x; i < n4; i += stride) {
        float4 v = reinterpret_cast<const float4*>(w)[i];
        f16x4v h = {(f16)v.x, (f16)v.y, (f16)v.z, (f16)v.w};
        reinterpret_cast<f16x4v*>(dst)[i] = h;
    }
}

__global__ void embed_kernel(const int* __restrict__ x, const float* __restrict__ emb,
                             bf16* __restrict__ xh, bf16* __restrict__ xl) {
    int row = blockIdx.x;
    int tok = x[row];
    const float4* src = reinterpret_cast<const float4*>(emb + (size_t)tok * HDIM);
    bf16x4* dh = reinterpret_cast<bf16x4*>(xh + (size_t)row * HDIM);
    bf16x4* dl = reinterpret_cast<bf16x4*>(xl + (size_t)row * HDIM);
    for (int i = threadIdx.x; i < HDIM / 4; i += blockDim.x) {
        float4 v = src[i];
        bf16 h0 = (bf16)v.x, h1 = (bf16)v.y, h2 = (bf16)v.z, h3 = (bf16)v.w;
        dh[i] = (bf16x4){h0, h1, h2, h3};
        dl[i] = (bf16x4){(bf16)(v.x - (float)h0), (bf16)(v.y - (float)h1),
                         (bf16)(v.z - (float)h2), (bf16)(v.w - (float)h3)};
    }
}

// initial h (fp16) stored at parity 1 (first reads occur at input-parity 1)
__global__ void init16_kernel(const float* __restrict__ h0, f16* __restrict__ hs16) {
    int i = blockIdx.x * blockDim.x + threadIdx.x;
    int l = i >> 16, r = i & 65535;
    hs16[(size_t)(l * 2 + 1) * 65536 + r] = (f16)h0[i];
}

// ---------------------------------------------------------------------------
// GEMM C = sum_p A_p B_p^T + bias (unchanged from r7)
// ---------------------------------------------------------------------------
__global__ __launch_bounds__(256) void gemm_bt(
    const bf16* __restrict__ a0, const bf16* __restrict__ a1, const bf16* __restrict__ a2,
    const bf16* __restrict__ b0, const bf16* __restrict__ b1, const bf16* __restrict__ b2,
    int npass, int K, const float* __restrict__ bias, float* __restrict__ C, int ldc) {
    __shared__ __align__(16) char As[128 * 128];
    __shared__ __align__(16) char Bs[128 * 128];
    const int tid = threadIdx.x;
    const int wid = tid >> 6, lane = tid & 63;
    const int l15 = lane & 15, l4 = lane >> 4;

    const int nbx = gridDim.x, mt = gridDim.y, nwg = nbx * mt;
    const int flat = blockIdx.y * nbx + blockIdx.x;
    const int xcd = flat & 7, o8 = flat >> 3;
    const int q8 = nwg >> 3, r8 = nwg & 7;
    const int wg = (xcd < r8 ? xcd * (q8 + 1) : r8 * (q8 + 1) + (xcd - r8) * q8) + o8;
    const int m0 = (wg % mt) * 128, n0 = (wg / mt) * 128;

    const int wr = (wid >> 1) * 64, wc = (wid & 1) * 64;
    const int swz_rd = (l15 & 7) << 4;
    const int rowL = lane >> 3;
    const int colE = (((lane & 7) ^ rowL)) << 3;

    f32x4 acc[4][4];
#pragma unroll
    for (int i = 0; i < 4; ++i)
#pragma unroll
        for (int j = 0; j < 4; ++j) acc[i][j] = (f32x4){0.f, 0.f, 0.f, 0.f};

    for (int p = 0; p < npass; ++p) {
        const bf16* A = (p == 0) ? a0 : ((p == 1) ? a1 : a2);
        const bf16* B = (p == 0) ? b0 : ((p == 1) ? b1 : b2);
        for (int k0 = 0; k0 < K; k0 += 64) {
            __syncthreads();
#pragma unroll
            for (int c2 = 0; c2 < 4; ++c2) {
                const int ch = wid * 4 + c2;
                const int row = ch * 8 + rowL;
                __builtin_amdgcn_global_load_lds(
                    (gas_void*)(A + (size_t)(m0 + row) * K + k0 + colE),
                    (las_void*)(As + ch * 1024), 16, 0, 0);
                __builtin_amdgcn_global_load_lds(
                    (gas_void*)(B + (size_t)(n0 + row) * K + k0 + colE),
                    (las_void*)(Bs + ch * 1024), 16, 0, 0);
            }
            __syncthreads();
#pragma unroll
            for (int ks = 0; ks < 2; ++ks) {
                const int cb = (ks * 64 + l4 * 16) ^ swz_rd;
                bf16x8 af[4], bfr[4];
#pragma unroll
                for (int mi = 0; mi < 4; ++mi)
                    af[mi] = *reinterpret_cast<const bf16x8*>(As + (wr + mi * 16 + l15) * 128 + cb);
#pragma unroll
                for (int ni = 0; ni < 4; ++ni)
                    bfr[ni] = *reinterpret_cast<const bf16x8*>(Bs + (wc + ni * 16 + l15) * 128 + cb);
#pragma unroll
                for (int mi = 0; mi < 4; ++mi)
#pragma unroll
                    for (int ni = 0; ni < 4; ++ni)
                        acc[mi][ni] = MFMA16(af[mi], bfr[ni], acc[mi][ni]);
            }
        }
    }
#pragma unroll
    for (int ni = 0; ni < 4; ++ni) {
        const int col = n0 + wc + ni * 16 + l15;
        const float bv = bias[col];
#pragma unroll
        for (int mi = 0; mi < 4; ++mi) {
            const int row0 = m0 + wr + mi * 16 + l4 * 4;
#pragma unroll
            for (int r = 0; r < 4; ++r)
                C[(size_t)(row0 + r) * ldc + col] = acc[mi][ni][r] + bv;
        }
    }
}

// ---------------------------------------------------------------------------
// Wavefront LSTM v10: r7 structure, fp16 single-pass (traffic/2, MFMA/3).
// 256 blocks x 512 thr; block owns 16 gate-cols. Chunk = 64 rows x 128 k f16:
// A 16KB + B 2x4KB = 24KB. 3 bufs, distance-3 issue, counted vmcnt, CBAR
// before reuse, WB2 store accounting, block-drain before gbar arrive.
// LDS: 3 x 24576 + pex 4096 = 77824.
// W0..W4 = Wh0, Wi1, Wh1, Wi2, Wh2 (fp16).
// ---------------------------------------------------------------------------
__global__ __launch_bounds__(512, 1) void lstm16(
    const float* __restrict__ cin,
    const f16* __restrict__ W0, const f16* __restrict__ W1, const f16* __restrict__ W2,
    const f16* __restrict__ W3, const f16* __restrict__ W4,
    const float* __restrict__ px0,
    const float* __restrict__ bh0, const float* __restrict__ bi1,
    const float* __restrict__ bh1, const float* __restrict__ bi2,
    const float* __restrict__ bh2,
    f16* __restrict__ hs16, bf16* __restrict__ outh, int* __restrict__ bar,
    f16* __restrict__ dumph, bf16* __restrict__ dumpo) {
    __shared__ __align__(16) char smem[77824];

    const int tid = threadIdx.x;
    const int lane = tid & 63, w = tid >> 6;
    const int l15 = lane & 15, l4 = lane >> 4;
    const int wm = w & 3, wn = w >> 2;
    const int j0 = blockIdx.x * 4;
    const int lq = l15 >> 2;
    const int lcol = lq * 1024 + j0 + (l15 & 3);
    // staging lane geometry (pre-swizzled global source, linear LDS dest)
    const int lr = lane >> 4;                  // 0..3
    const int lp = lane & 15;                  // 16B piece
    const int ar0 = w * 8 + lr, ar1 = w * 8 + 4 + lr;
    const size_t aoff0 = (size_t)ar0 * HDIM + (size_t)((lp ^ (ar0 & 15)) * 8);
    const size_t aoff1 = (size_t)ar1 * HDIM + (size_t)((lp ^ (ar1 & 15)) * 8);
    const int adst0 = w * 2048, adst1 = w * 2048 + 1024;
    const int cr = (w >> 1) * 4 + lr;          // B col-row 0..15
    const size_t boff = (size_t)((cr >> 2) * 1024 + j0 + (cr & 3)) * HDIM +
                        (size_t)((lp ^ cr) * 8);
    const int bdst = 16384 + (w & 1) * 4096 + (w >> 1) * 1024;
    // fragment reads
    const int a_frow = (wm * 16 + l15) * 256;
    const int b_frow = l15 * 256;
    const int swz_r = l15 << 4;
    const int kbh = wn * 128;
    // gates
    const int gb = tid >> 2, gj = tid & 3;

    float biasv0 = 0.f, biasv1 = 0.f, biasv2 = 0.f;
    if (wn == 0) {
        biasv0 = bh0[lcol];
        biasv1 = bi1[lcol] + bh1[lcol];
        biasv2 = bi2[lcol] + bh2[lcol];
    }
    float creg0 = 0.f, creg1 = 0.f, creg2 = 0.f;
    if (tid < 256) {
        creg0 = cin[0 * 65536 + gb * 1024 + j0 + gj];
        creg1 = cin[1 * 65536 + gb * 1024 + j0 + gj];
        creg2 = cin[2 * 65536 + gb * 1024 + j0 + gj];
    }
    asm volatile("s_waitcnt vmcnt(0) lgkmcnt(0)" ::: "memory");
    __syncthreads();

    auto hsp = [&](int l, int par) { return hs16 + (size_t)(l * 2 + par) * 65536; };

    int barid = 0;

#define WB(N)                                                                    \
    {                                                                            \
        asm volatile("s_waitcnt vmcnt(" #N ")" ::: "memory");                    \
        __builtin_amdgcn_s_barrier();                                            \
        __builtin_amdgcn_sched_barrier(0);                                       \
    }
#define WB2(N0, N1)                                                              \
    {                                                                            \
        if (wn == 0) asm volatile("s_waitcnt vmcnt(" #N0 ")" ::: "memory");      \
        else         asm volatile("s_waitcnt vmcnt(" #N1 ")" ::: "memory");      \
        __builtin_amdgcn_s_barrier();                                            \
        __builtin_amdgcn_sched_barrier(0);                                       \
    }
#define CBAR()                                                                   \
    {                                                                            \
        asm volatile("s_waitcnt lgkmcnt(0)" ::: "memory");                       \
        __builtin_amdgcn_s_barrier();                                            \
        __builtin_amdgcn_sched_barrier(0);                                       \
    }

// 3 loads/wave/chunk: 2 A (4 rows each) + 1 B (4 col-rows of one matrix)
#define ISSUE(c, buf)                                                            \
    {                                                                            \
        const int g_ = ((c) < 8) ? 0 : ((c) < 16) ? 1 : 2;                       \
        const f16* pa_ = (g_ == 0) ? A0 : (g_ == 1) ? A1 : A2;                   \
        const f16* pb_;                                                          \
        if ((w & 1) == 0) pb_ = (g_ == 0) ? W0 : (g_ == 1) ? W2 : W4;            \
        else              pb_ = (g_ == 0) ? W1 : (g_ == 1) ? W3 : W4;            \
        const size_t k0_ = (size_t)(((c) & 7) * 128);                            \
        char* base_ = smem + (buf) * 24576;                                      \
        __builtin_amdgcn_global_load_lds((gas_void*)(pa_ + aoff0 + k0_),         \
                                         (las_void*)(base_ + adst0), 16, 0, 0);  \
        __builtin_amdgcn_global_load_lds((gas_void*)(pa_ + aoff1 + k0_),         \
                                         (las_void*)(base_ + adst1), 16, 0, 0);  \
        __builtin_amdgcn_global_load_lds((gas_void*)(pb_ + boff + k0_),          \
                                         (las_void*)(base_ + bdst), 16, 0, 0);   \
    }

#define COMPUTE(buf, ACCX, ACCY, TWO, AX, AY)                                    \
    {                                                                            \
        const char* base_ = smem + (buf) * 24576;                                \
        _Pragma("unroll") for (int ks_ = 0; ks_ < 2; ++ks_) {                    \
            const int kb_ = kbh + ks_ * 64 + l4 * 16;                            \
            const int co_ = kb_ ^ swz_r;                                         \
            f16x8 af_ = *reinterpret_cast<const f16x8*>(base_ + a_frow + co_);   \
            f16x8 b0_ = *reinterpret_cast<const f16x8*>(base_ + 16384 + b_frow + co_); \
            if (AX) ACCX = MFMAH(af_, b0_, ACCX);                                \
            if (TWO) {                                                           \
                f16x8 b1_ = *reinterpret_cast<const f16x8*>(base_ + 20480 + b_frow + co_); \
                if (AY) ACCY = MFMAH(af_, b1_, ACCY);                            \
            }                                                                    \
        }                                                                        \
    }

#define EPILOGUE(ACC, BIASV, USEPX, ACT, HD, OH, CREG)                           \
    {                                                                            \
        float* pex = reinterpret_cast<float*>(smem + 73728);                     \
        if (wn == 0) {                                                           \
            _Pragma("unroll") for (int r = 0; r < 4; ++r) {                      \
                const int row = wm * 16 + l4 * 4 + r;                            \
                float v = ACC[r] + (BIASV);                                      \
                if (USEPX) v += pxv[r];                                          \
                pex[row * 16 + l15] = v;                                         \
            }                                                                    \
        }                                                                        \
        CBAR();                                                                  \
        if (wn == 1) {                                                           \
            _Pragma("unroll") for (int r = 0; r < 4; ++r)                        \
                pex[(wm * 16 + l4 * 4 + r) * 16 + l15] += ACC[r];                \
        }                                                                        \
        CBAR();                                                                  \
        if (tid < 256) {                                                         \
            const float pi = pex[gb * 16 + 0 + gj];                              \
            const float pf = pex[gb * 16 + 4 + gj];                              \
            const float po = pex[gb * 16 + 8 + gj];                              \
            const float pg = pex[gb * 16 + 12 + gj];                             \
            const float ig = 1.f / (1.f + expf(-pi));                            \
            const float fg = 1.f / (1.f + expf(-pf));                            \
            const float og = 1.f / (1.f + expf(-po));                            \
            const float gg = tanhf(pg);                                          \
            const float c2v = fg * (CREG) + ig * gg;                             \
            const float h2v = og * tanhf(c2v);                                   \
            if (ACT) (CREG) = c2v;                                               \
            const int idx = gb * 1024 + j0 + gj;                                 \
            (HD)[idx] = (f16)h2v;                                                \
            (OH)[idx] = (bf16)h2v;                                               \
        }                                                                        \
    }

#pragma unroll 1
    for (int s = 0; s < T_LEN + 2; ++s) {
        const int ps = s & 1;
        const bool act0 = (s < T_LEN);
        const bool act1 = (s >= 1) && (s <= T_LEN);
        const bool act2 = (s >= 2);

        const f16* A0 = hsp(0, 1 - ps);
        const f16* A1 = hsp(1, ps);
        const f16* A2 = hsp(2, 1 - ps);
        f16* d0 = act0 ? hsp(0, ps)     : dumph;
        f16* d1 = act1 ? hsp(1, 1 - ps) : dumph;
        f16* d2 = act2 ? hsp(2, ps)     : dumph;
        bf16* ohp = act2 ? (outh + (size_t)(s - 2) * 65536) : dumpo;

        float pxv[4] = {0.f, 0.f, 0.f, 0.f};
        if (wn == 0 && act0) {
            const float* pxr = px0 + (size_t)s * (BATCH * GDIM) +
                               (size_t)(wm * 16 + l4 * 4) * GDIM + lcol;
#pragma unroll
            for (int r = 0; r < 4; ++r) pxv[r] = pxr[(size_t)r * GDIM];
        }

        f32x4 acc0 = (f32x4){0.f, 0.f, 0.f, 0.f};
        f32x4 acc1 = (f32x4){0.f, 0.f, 0.f, 0.f};
        f32x4 acc2 = (f32x4){0.f, 0.f, 0.f, 0.f};

        ISSUE(0, 0) ISSUE(1, 1) ISSUE(2, 2)

        // ---- group 0: acc0 += A0*Wh0 ; acc1 += A0*Wi1 ----
        WB(6)     COMPUTE(0, acc0, acc1, 1, act0, act1) CBAR() ISSUE(3, 0)
        WB(6)     COMPUTE(1, acc0, acc1, 1, act0, act1) CBAR() ISSUE(4, 1)
        WB(6)     COMPUTE(2, acc0, acc1, 1, act0, act1) CBAR() ISSUE(5, 2)
        WB(6)     COMPUTE(0, acc0, acc1, 1, act0, act1) CBAR() ISSUE(6, 0)
        WB(6)     COMPUTE(1, acc0, acc1, 1, act0, act1) CBAR() ISSUE(7, 1)
        WB(6)     COMPUTE(2, acc0, acc1, 1, act0, act1) CBAR() ISSUE(8, 2)
        WB(6)     COMPUTE(0, acc0, acc1, 1, act0, act1) CBAR() ISSUE(9, 0)
        WB(6)     COMPUTE(1, acc0, acc1, 1, act0, act1) CBAR() ISSUE(10, 1)
        EPILOGUE(acc0, biasv0, 1, act0, d0, dumpo, creg0)
        // ---- group 1: acc1 += A1*Wh1 ; acc2 += A1*Wi2 ----
        WB2(8, 6) COMPUTE(2, acc1, acc2, 1, act1, act2) CBAR() ISSUE(11, 2)
        WB2(8, 6) COMPUTE(0, acc1, acc2, 1, act1, act2) CBAR() ISSUE(12, 0)
        WB(6)     COMPUTE(1, acc1, acc2, 1, act1, act2) CBAR() ISSUE(13, 1)
        WB(6)     COMPUTE(2, acc1, acc2, 1, act1, act2) CBAR() ISSUE(14, 2)
        WB(6)     COMPUTE(0, acc1, acc2, 1, act1, act2) CBAR() ISSUE(15, 0)
        WB(6)     COMPUTE(1, acc1, acc2, 1, act1, act2) CBAR() ISSUE(16, 1)
        WB(6)     COMPUTE(2, acc1, acc2, 1, act1, act2) CBAR() ISSUE(17, 2)
        WB(6)     COMPUTE(0, acc1, acc2, 1, act1, act2) CBAR() ISSUE(18, 0)
        EPILOGUE(acc1, biasv1, 0, act1, d1, dumpo, creg1)
        // ---- group 2: acc2 += A2*Wh2 ----
        WB2(8, 6) COMPUTE(1, acc2, acc2, 0, act2, act2) CBAR() ISSUE(19, 1)
        WB2(8, 6) COMPUTE(2, acc2, acc2, 0, act2, act2) CBAR() ISSUE(20, 2)
        WB(6)     COMPUTE(0, acc2, acc2, 0, act2, act2) CBAR() ISSUE(21, 0)
        WB(6)     COMPUTE(1, acc2, acc2, 0, act2, act2) CBAR() ISSUE(22, 1)
        WB(6)     COMPUTE(2, acc2, acc2, 0, act2, act2) CBAR() ISSUE(23, 2)
        WB(6)     COMPUTE(0, acc2, acc2, 0, act2, act2) CBAR()
        WB(3)     COMPUTE(1, acc2, acc2, 0, act2, act2) CBAR()
        WB(0)     COMPUTE(2, acc2, acc2, 0, act2, act2) CBAR()
        EPILOGUE(acc2, biasv2, 0, act2, d2, ohp, creg2)

        // ---- block-wide drain, then grid barrier ----
        if (s < T_LEN + 1) {
            asm volatile("s_waitcnt vmcnt(0) lgkmcnt(0)" ::: "memory");
            __builtin_amdgcn_s_barrier();
            __builtin_amdgcn_sched_barrier(0);
            if (tid == 0) {
                __hip_atomic_fetch_add(&bar[barid], 1, __ATOMIC_RELEASE,
                                       __HIP_MEMORY_SCOPE_AGENT);
                while (__hip_atomic_load(&bar[barid], __ATOMIC_RELAXED,
                                         __HIP_MEMORY_SCOPE_AGENT) < (int)gridDim.x)
                    __builtin_amdgcn_s_sleep(8);
                __builtin_amdgcn_fence(__ATOMIC_ACQUIRE, "agent");
            }
            ++barid;
            __builtin_amdgcn_s_barrier();
            __builtin_amdgcn_sched_barrier(0);
        }
    }
#undef WB
#undef WB2
#undef CBAR
#undef ISSUE
#undef COMPUTE
#undef EPILOGUE
}

// ---------------------------------------------------------------------------
extern "C" void kernel_launch(void* const* d_in, const int* in_sizes, int n_in,
                              void* d_out, int out_size, void* d_ws, size_t ws_size,
                              hipStream_t stream) {
    (void)in_sizes; (void)n_in; (void)out_size; (void)ws_size;
    const int*   x   = (const int*)d_in[0];
    const float* h0  = (const float*)d_in[1];
    const float* c0  = (const float*)d_in[2];
    const float* emb = (const float*)d_in[3];
    const float* W[6] = { (const float*)d_in[4],  (const float*)d_in[6],
                          (const float*)d_in[8],  (const float*)d_in[10],
                          (const float*)d_in[12], (const float*)d_in[14] };
    const float* bi0 = (const float*)d_in[5];
    const float* bh0 = (const float*)d_in[7];
    const float* bi1 = (const float*)d_in[9];
    const float* bh1 = (const float*)d_in[11];
    const float* bi2 = (const float*)d_in[13];
    const float* bh2 = (const float*)d_in[15];
    const float* Wd  = (const float*)d_in[16];
    const float* bd  = (const float*)d_in[17];

    char* ws = (char*)d_ws;
    size_t off = 0;
    float* px0 = (float*)(ws + off); off += (size_t)TBROW * GDIM * 4;
    bf16* wsp0 = (bf16*)(ws + off); off += (size_t)GDIM * HDIM * 2;   // Wi0 hi
    bf16* wsp1 = (bf16*)(ws + off); off += (size_t)GDIM * HDIM * 2;   // Wi0 lo
    bf16* wdb  = (bf16*)(ws + off); off += (size_t)VOCAB * HDIM * 2;
    bf16* xeh  = (bf16*)(ws + off); off += (size_t)TBROW * HDIM * 2;
    bf16* xel  = (bf16*)(ws + off); off += (size_t)TBROW * HDIM * 2;
    bf16* outh = (bf16*)(ws + off); off += (size_t)TBROW * HDIM * 2;
    f16* w16[5];
    for (int i = 0; i < 5; ++i) { w16[i] = (f16*)(ws + off); off += (size_t)GDIM * HDIM * 2; }
    f16* hs16  = (f16*)(ws + off); off += (size_t)6 * BATCH * HDIM * 2;
    int* bar   = (int*)(ws + off); off += 1024;
    f16* dumph = (f16*)(ws + off); off += (size_t)BATCH * HDIM * 2;
    bf16* dumpo = (bf16*)(ws + off); off += (size_t)BATCH * HDIM * 2;

    // Wi0 split (for px0), Wd bf16, recurrence weights fp16
    split_kernel<<<1024, 256, 0, stream>>>(W[0], wsp0, wsp1, GDIM * HDIM / 4);
    conv_kernel<<<2048, 256, 0, stream>>>(Wd, wdb, VOCAB * HDIM / 4);
    for (int i = 0; i < 5; ++i)
        conv16_kernel<<<1024, 256, 0, stream>>>(W[i + 1], w16[i], GDIM * HDIM / 4);
    embed_kernel<<<TBROW, 256, 0, stream>>>(x, emb, xeh, xel);
    init16_kernel<<<768, 256, 0, stream>>>(h0, hs16);
    (void)hipMemsetAsync(bar, 0, 1024, stream);

    // px0 = xe @ Wi0^T + bi0 (split-3, fp32-accurate)
    dim3 gpx(GDIM / 128, TBROW / 128);
    gemm_bt<<<gpx, 256, 0, stream>>>(xeh, xel, xeh, wsp0, wsp0, wsp1,
                                     3, HDIM, bi0, px0, GDIM);

    // whole recurrence: fp16 single-pass wavefront
    lstm16<<<256, 512, 0, stream>>>(
        c0, w16[0], w16[1], w16[2], w16[3], w16[4],
        px0, bh0, bi1, bh1, bi2, bh2,
        hs16, outh, bar, dumph, dumpo);

    // decoder: d_out = outh @ Wd^T + bd
    dim3 gdec(VOCAB / 128, TBROW / 128);
    gemm_bt<<<gdec, 256, 0, stream>>>(outh, nullptr, nullptr, wdb, nullptr, nullptr,
                                      1, HDIM, bd, (float*)d_out, VOCAB);
}

// Round 15
// 2104.010 us; speedup vs baseline: 7.3747x; 1.1846x over previous
//
#include <hip/hip_runtime.h>

typedef __bf16 bf16;
typedef __bf16 bf16x8 __attribute__((ext_vector_type(8)));
typedef __bf16 bf16x4 __attribute__((ext_vector_type(4)));
typedef float  f32x4  __attribute__((ext_vector_type(4)));
typedef _Float16 f16;
typedef _Float16 f16x8 __attribute__((ext_vector_type(8)));
typedef _Float16 f16x4v __attribute__((ext_vector_type(4)));

#define T_LEN 70
#define BATCH 64
#define HDIM  1024
#define GDIM  4096
#define VOCAB 32000
#define TBROW (T_LEN * BATCH)   // 4480

#define MFMA16(a, b, c) __builtin_amdgcn_mfma_f32_16x16x32_bf16((a), (b), (c), 0, 0, 0)
#define MFMAH(a, b, c)  __builtin_amdgcn_mfma_f32_16x16x32_f16((a), (b), (c), 0, 0, 0)

typedef const __attribute__((address_space(1))) void gas_void;
typedef __attribute__((address_space(3))) void las_void;

// ---------------------------------------------------------------------------
__global__ void split_kernel(const float* __restrict__ w, bf16* __restrict__ hi,
                             bf16* __restrict__ lo, int n4) {
    int stride = gridDim.x * blockDim.x;
    for (int i = blockIdx.x * blockDim.x + threadIdx.x; i < n4; i += stride) {
        float4 v = reinterpret_cast<const float4*>(w)[i];
        bf16 h0 = (bf16)v.x, h1 = (bf16)v.y, h2 = (bf16)v.z, h3 = (bf16)v.w;
        bf16x4 hv = {h0, h1, h2, h3};
        bf16x4 lv = {(bf16)(v.x - (float)h0), (bf16)(v.y - (float)h1),
                     (bf16)(v.z - (float)h2), (bf16)(v.w - (float)h3)};
        reinterpret_cast<bf16x4*>(hi)[i] = hv;
        reinterpret_cast<bf16x4*>(lo)[i] = lv;
    }
}

__global__ void conv_kernel(const float* __restrict__ w, bf16* __restrict__ hi, int n4) {
    int stride = gridDim.x * blockDim.x;
    for (int i = blockIdx.x * blockDim.x + threadIdx.x; i < n4; i += stride) {
        float4 v = reinterpret_cast<const float4*>(w)[i];
        bf16x4 hv = {(bf16)v.x, (bf16)v.y, (bf16)v.z, (bf16)v.w};
        reinterpret_cast<bf16x4*>(hi)[i] = hv;
    }
}

__global__ void conv16_kernel(const float* __restrict__ w, f16* __restrict__ dst, int n4) {
    int stride = gridDim.x * blockDim.x;
    for (int i = blockIdx.x * blockDim.x + threadIdx.x; i < n4; i += stride) {
        float4 v = reinterpret_cast<const float4*>(w)[i];
        f16x4v h = {(f16)v.x, (f16)v.y, (f16)v.z, (f16)v.w};
        reinterpret_cast<f16x4v*>(dst)[i] = h;
    }
}

__global__ void embed_kernel(const int* __restrict__ x, const float* __restrict__ emb,
                             bf16* __restrict__ xh, bf16* __restrict__ xl) {
    int row = blockIdx.x;
    int tok = x[row];
    const float4* src = reinterpret_cast<const float4*>(emb + (size_t)tok * HDIM);
    bf16x4* dh = reinterpret_cast<bf16x4*>(xh + (size_t)row * HDIM);
    bf16x4* dl = reinterpret_cast<bf16x4*>(xl + (size_t)row * HDIM);
    for (int i = threadIdx.x; i < HDIM / 4; i += blockDim.x) {
        float4 v = src[i];
        bf16 h0 = (bf16)v.x, h1 = (bf16)v.y, h2 = (bf16)v.z, h3 = (bf16)v.w;
        dh[i] = (bf16x4){h0, h1, h2, h3};
        dl[i] = (bf16x4){(bf16)(v.x - (float)h0), (bf16)(v.y - (float)h1),
                         (bf16)(v.z - (float)h2), (bf16)(v.w - (float)h3)};
    }
}

// initial h (fp16) stored at parity 1 (first reads occur at input-parity 1)
__global__ void init16_kernel(const float* __restrict__ h0, f16* __restrict__ hs16) {
    int i = blockIdx.x * blockDim.x + threadIdx.x;
    int l = i >> 16, r = i & 65535;
    hs16[(size_t)(l * 2 + 1) * 65536 + r] = (f16)h0[i];
}

// ---------------------------------------------------------------------------
// GEMM C = sum_p A_p B_p^T + bias (unchanged from r7)
// ---------------------------------------------------------------------------
__global__ __launch_bounds__(256) void gemm_bt(
    const bf16* __restrict__ a0, const bf16* __restrict__ a1, const bf16* __restrict__ a2,
    const bf16* __restrict__ b0, const bf16* __restrict__ b1, const bf16* __restrict__ b2,
    int npass, int K, const float* __restrict__ bias, float* __restrict__ C, int ldc) {
    __shared__ __align__(16) char As[128 * 128];
    __shared__ __align__(16) char Bs[128 * 128];
    const int tid = threadIdx.x;
    const int wid = tid >> 6, lane = tid & 63;
    const int l15 = lane & 15, l4 = lane >> 4;

    const int nbx = gridDim.x, mt = gridDim.y, nwg = nbx * mt;
    const int flat = blockIdx.y * nbx + blockIdx.x;
    const int xcd = flat & 7, o8 = flat >> 3;
    const int q8 = nwg >> 3, r8 = nwg & 7;
    const int wg = (xcd < r8 ? xcd * (q8 + 1) : r8 * (q8 + 1) + (xcd - r8) * q8) + o8;
    const int m0 = (wg % mt) * 128, n0 = (wg / mt) * 128;

    const int wr = (wid >> 1) * 64, wc = (wid & 1) * 64;
    const int swz_rd = (l15 & 7) << 4;
    const int rowL = lane >> 3;
    const int colE = (((lane & 7) ^ rowL)) << 3;

    f32x4 acc[4][4];
#pragma unroll
    for (int i = 0; i < 4; ++i)
#pragma unroll
        for (int j = 0; j < 4; ++j) acc[i][j] = (f32x4){0.f, 0.f, 0.f, 0.f};

    for (int p = 0; p < npass; ++p) {
        const bf16* A = (p == 0) ? a0 : ((p == 1) ? a1 : a2);
        const bf16* B = (p == 0) ? b0 : ((p == 1) ? b1 : b2);
        for (int k0 = 0; k0 < K; k0 += 64) {
            __syncthreads();
#pragma unroll
            for (int c2 = 0; c2 < 4; ++c2) {
                const int ch = wid * 4 + c2;
                const int row = ch * 8 + rowL;
                __builtin_amdgcn_global_load_lds(
                    (gas_void*)(A + (size_t)(m0 + row) * K + k0 + colE),
                    (las_void*)(As + ch * 1024), 16, 0, 0);
                __builtin_amdgcn_global_load_lds(
                    (gas_void*)(B + (size_t)(n0 + row) * K + k0 + colE),
                    (las_void*)(Bs + ch * 1024), 16, 0, 0);
            }
            __syncthreads();
#pragma unroll
            for (int ks = 0; ks < 2; ++ks) {
                const int cb = (ks * 64 + l4 * 16) ^ swz_rd;
                bf16x8 af[4], bfr[4];
#pragma unroll
                for (int mi = 0; mi < 4; ++mi)
                    af[mi] = *reinterpret_cast<const bf16x8*>(As + (wr + mi * 16 + l15) * 128 + cb);
#pragma unroll
                for (int ni = 0; ni < 4; ++ni)
                    bfr[ni] = *reinterpret_cast<const bf16x8*>(Bs + (wc + ni * 16 + l15) * 128 + cb);
#pragma unroll
                for (int mi = 0; mi < 4; ++mi)
#pragma unroll
                    for (int ni = 0; ni < 4; ++ni)
                        acc[mi][ni] = MFMA16(af[mi], bfr[ni], acc[mi][ni]);
            }
        }
    }
#pragma unroll
    for (int ni = 0; ni < 4; ++ni) {
        const int col = n0 + wc + ni * 16 + l15;
        const float bv = bias[col];
#pragma unroll
        for (int mi = 0; mi < 4; ++mi) {
            const int row0 = m0 + wr + mi * 16 + l4 * 4;
#pragma unroll
            for (int r = 0; r < 4; ++r)
                C[(size_t)(row0 + r) * ldc + col] = acc[mi][ni][r] + bv;
        }
    }
}

// ---------------------------------------------------------------------------
// Wavefront LSTM v11 = v10 + LDS-pinned weights for Wh0/Wi1/Wh1 (96 KB,
// loaded once, reused all 72 supersteps). Only Wi2 (group 1) and Wh2
// (group 2) stream (16 MB/superstep instead of 40). 2 stream bufs,
// distance-2, counted vmcnt (per-wave FIFO-derived table), CBAR before
// buffer reuse, dup-B region keeps per-wave load counts uniform.
// LDS: pinned 3x32768 | bufs 2x24576 @98304 (A 16K, B 4K, dup 4K) |
//      pex 4096 @147456 -> 151552 total.
// ---------------------------------------------------------------------------
__global__ __launch_bounds__(512, 1) void lstm16(
    const float* __restrict__ cin,
    const f16* __restrict__ W0, const f16* __restrict__ W1, const f16* __restrict__ W2,
    const f16* __restrict__ W3, const f16* __restrict__ W4,
    const float* __restrict__ px0,
    const float* __restrict__ bh0, const float* __restrict__ bi1,
    const float* __restrict__ bh1, const float* __restrict__ bi2,
    const float* __restrict__ bh2,
    f16* __restrict__ hs16, bf16* __restrict__ outh, int* __restrict__ bar,
    f16* __restrict__ dumph, bf16* __restrict__ dumpo) {
    __shared__ __align__(16) char smem[151552];

    const int tid = threadIdx.x;
    const int lane = tid & 63, w = tid >> 6;
    const int l15 = lane & 15, l4 = lane >> 4;
    const int wm = w & 3, wn = w >> 2;
    const int j0 = blockIdx.x * 4;
    const int lq = l15 >> 2;
    const int lcol = lq * 1024 + j0 + (l15 & 3);
    // staging lane geometry
    const int lr = lane >> 4;                  // 0..3
    const int lp = lane & 15;                  // 16B piece
    const int ar0 = w * 8 + lr, ar1 = w * 8 + 4 + lr;
    const size_t aoff0 = (size_t)ar0 * HDIM + (size_t)((lp ^ (ar0 & 15)) * 8);
    const size_t aoff1 = (size_t)ar1 * HDIM + (size_t)((lp ^ (ar1 & 15)) * 8);
    const int adst0 = w * 2048, adst1 = w * 2048 + 1024;
    // stream-B: cr = (w&3)*4 + lr ; waves 4-7 mirror into dup region
    const int crS = (w & 3) * 4 + lr;
    const size_t boffS = (size_t)((crS >> 2) * 1024 + j0 + (crS & 3)) * HDIM +
                         (size_t)((lp ^ crS) * 8);
    const int bdstS = 16384 + ((w & 4) >> 2) * 4096 + (w & 3) * 1024;
    // fragment reads
    const int a_frow = (wm * 16 + l15) * 256;
    const int b_frow = l15 * 256;
    const int swz_r = l15 << 4;
    const int kbh = wn * 128;
    // gates
    const int gb = tid >> 2, gj = tid & 3;

    float biasv0 = 0.f, biasv1 = 0.f, biasv2 = 0.f;
    if (wn == 0) {
        biasv0 = bh0[lcol];
        biasv1 = bi1[lcol] + bh1[lcol];
        biasv2 = bi2[lcol] + bh2[lcol];
    }
    float creg0 = 0.f, creg1 = 0.f, creg2 = 0.f;
    if (tid < 256) {
        creg0 = cin[0 * 65536 + gb * 1024 + j0 + gj];
        creg1 = cin[1 * 65536 + gb * 1024 + j0 + gj];
        creg2 = cin[2 * 65536 + gb * 1024 + j0 + gj];
    }

    // ---- pin Wh0(W0), Wi1(W1), Wh1(W2) into LDS [0, 98304) ----
    // layout per matrix: 8 chunk-blocks x 4KB, internal = stream-B layout.
    {
        const f16* wp[3] = {W0, W1, W2};
#pragma unroll
        for (int it = 0; it < 12; ++it) {
            const int u = w * 12 + it;            // 0..95
            const int m = u >> 5, c = (u >> 2) & 7, q = u & 3;
            const int cr = q * 4 + lr;
            const size_t src = (size_t)((cr >> 2) * 1024 + j0 + (cr & 3)) * HDIM +
                               (size_t)(c * 128) + (size_t)((lp ^ cr) * 8);
            __builtin_amdgcn_global_load_lds(
                (gas_void*)(wp[m] + src),
                (las_void*)(smem + m * 32768 + c * 4096 + q * 1024), 16, 0, 0);
        }
    }
    asm volatile("s_waitcnt vmcnt(0) lgkmcnt(0)" ::: "memory");
    __syncthreads();

    auto hsp = [&](int l, int par) { return hs16 + (size_t)(l * 2 + par) * 65536; };

    int barid = 0;

#define WB(N)                                                                    \
    {                                                                            \
        asm volatile("s_waitcnt vmcnt(" #N ")" ::: "memory");                    \
        __builtin_amdgcn_s_barrier();                                            \
        __builtin_amdgcn_sched_barrier(0);                                       \
    }
#define WB2(N0, N1)                                                              \
    {                                                                            \
        if (w < 4) asm volatile("s_waitcnt vmcnt(" #N0 ")" ::: "memory");        \
        else       asm volatile("s_waitcnt vmcnt(" #N1 ")" ::: "memory");        \
        __builtin_amdgcn_s_barrier();                                            \
        __builtin_amdgcn_sched_barrier(0);                                       \
    }
#define CBAR()                                                                   \
    {                                                                            \
        asm volatile("s_waitcnt lgkmcnt(0)" ::: "memory");                       \
        __builtin_amdgcn_s_barrier();                                            \
        __builtin_amdgcn_sched_barrier(0);                                       \
    }

// 2 A loads always; +1 stream-B load for chunks >= 8 (g1: Wi2=W3, g2: Wh2=W4)
#define ISSUE(c, buf)                                                            \
    {                                                                            \
        const int g_ = ((c) < 8) ? 0 : ((c) < 16) ? 1 : 2;                       \
        const f16* pa_ = (g_ == 0) ? A0 : (g_ == 1) ? A1 : A2;                   \
        const size_t k0_ = (size_t)(((c) & 7) * 128);                            \
        char* base_ = smem + 98304 + (buf) * 24576;                              \
        __builtin_amdgcn_global_load_lds((gas_void*)(pa_ + aoff0 + k0_),         \
                                         (las_void*)(base_ + adst0), 16, 0, 0);  \
        __builtin_amdgcn_global_load_lds((gas_void*)(pa_ + aoff1 + k0_),         \
                                         (las_void*)(base_ + adst1), 16, 0, 0);  \
        if ((c) >= 8) {                                                          \
            const f16* pb_ = ((c) < 16) ? W3 : W4;                               \
            __builtin_amdgcn_global_load_lds((gas_void*)(pb_ + boffS + k0_),     \
                                             (las_void*)(base_ + bdstS), 16, 0, 0); \
        }                                                                        \
    }

// G=0: acc0 += A*Wh0(pin0), acc1 += A*Wi1(pin1)
// G=1: acc1 += A*Wh1(pin2), acc2 += A*Wi2(stream)
// G=2: acc2 += A*Wh2(stream)
#define COMPUTE(buf, cc, G)                                                      \
    {                                                                            \
        const char* base_ = smem + 98304 + (buf) * 24576;                        \
        const char* pin_ = smem + ((G) == 0 ? 0 : 65536) + ((cc) & 7) * 4096;    \
        const char* pin1_ = smem + 32768 + ((cc) & 7) * 4096;                    \
        _Pragma("unroll") for (int ks_ = 0; ks_ < 2; ++ks_) {                    \
            const int kb_ = kbh + ks_ * 64 + l4 * 16;                            \
            const int co_ = kb_ ^ swz_r;                                         \
            f16x8 af_ = *reinterpret_cast<const f16x8*>(base_ + a_frow + co_);   \
            if ((G) == 0) {                                                      \
                f16x8 b0_ = *reinterpret_cast<const f16x8*>(pin_ + b_frow + co_);  \
                f16x8 b1_ = *reinterpret_cast<const f16x8*>(pin1_ + b_frow + co_); \
                if (act0) acc0 = MFMAH(af_, b0_, acc0);                          \
                if (act1) acc1 = MFMAH(af_, b1_, acc1);                          \
            } else if ((G) == 1) {                                               \
                f16x8 b0_ = *reinterpret_cast<const f16x8*>(pin_ + b_frow + co_);  \
                f16x8 b1_ = *reinterpret_cast<const f16x8*>(base_ + 16384 + b_frow + co_); \
                if (act1) acc1 = MFMAH(af_, b0_, acc1);                          \
                if (act2) acc2 = MFMAH(af_, b1_, acc2);                          \
            } else {                                                             \
                f16x8 b0_ = *reinterpret_cast<const f16x8*>(base_ + 16384 + b_frow + co_); \
                if (act2) acc2 = MFMAH(af_, b0_, acc2);                          \
            }                                                                    \
        }                                                                        \
    }

#define EPILOGUE(ACC, BIASV, USEPX, ACT, HD, OH, CREG)                           \
    {                                                                            \
        float* pex = reinterpret_cast<float*>(smem + 147456);                    \
        if (wn == 0) {                                                           \
            _Pragma("unroll") for (int r = 0; r < 4; ++r) {                      \
                const int row = wm * 16 + l4 * 4 + r;                            \
                float v = ACC[r] + (BIASV);                                      \
                if (USEPX) v += pxv[r];                                          \
                pex[row * 16 + l15] = v;                                         \
            }                                                                    \
        }                                                                        \
        CBAR();                                                                  \
        if (wn == 1) {                                                           \
            _Pragma("unroll") for (int r = 0; r < 4; ++r)                        \
                pex[(wm * 16 + l4 * 4 + r) * 16 + l15] += ACC[r];                \
        }                                                                        \
        CBAR();                                                                  \
        if (tid < 256) {                                                         \
            const float pi = pex[gb * 16 + 0 + gj];                              \
            const float pf = pex[gb * 16 + 4 + gj];                              \
            const float po = pex[gb * 16 + 8 + gj];                              \
            const float pg = pex[gb * 16 + 12 + gj];                             \
            const float ig = 1.f / (1.f + expf(-pi));                            \
            const float fg = 1.f / (1.f + expf(-pf));                            \
            const float og = 1.f / (1.f + expf(-po));                            \
            const float gg = tanhf(pg);                                          \
            const float c2v = fg * (CREG) + ig * gg;                             \
            const float h2v = og * tanhf(c2v);                                   \
            if (ACT) (CREG) = c2v;                                               \
            const int idx = gb * 1024 + j0 + gj;                                 \
            (HD)[idx] = (f16)h2v;                                                \
            (OH)[idx] = (bf16)h2v;                                               \
        }                                                                        \
    }

#pragma unroll 1
    for (int s = 0; s < T_LEN + 2; ++s) {
        const int ps = s & 1;
        const bool act0 = (s < T_LEN);
        const bool act1 = (s >= 1) && (s <= T_LEN);
        const bool act2 = (s >= 2);

        const f16* A0 = hsp(0, 1 - ps);
        const f16* A1 = hsp(1, ps);
        const f16* A2 = hsp(2, 1 - ps);
        f16* d0 = act0 ? hsp(0, ps)     : dumph;
        f16* d1 = act1 ? hsp(1, 1 - ps) : dumph;
        f16* d2 = act2 ? hsp(2, ps)     : dumph;
        bf16* ohp = act2 ? (outh + (size_t)(s - 2) * 65536) : dumpo;

        float pxv[4] = {0.f, 0.f, 0.f, 0.f};
        if (wn == 0 && act0) {
            const float* pxr = px0 + (size_t)s * (BATCH * GDIM) +
                               (size_t)(wm * 16 + l4 * 4) * GDIM + lcol;
#pragma unroll
            for (int r = 0; r < 4; ++r) pxv[r] = pxr[(size_t)r * GDIM];
        }

        f32x4 acc0 = (f32x4){0.f, 0.f, 0.f, 0.f};
        f32x4 acc1 = (f32x4){0.f, 0.f, 0.f, 0.f};
        f32x4 acc2 = (f32x4){0.f, 0.f, 0.f, 0.f};

        ISSUE(0, 0) ISSUE(1, 1)

        // ---- group 0 (pinned Wh0/Wi1): chunks 0-7 ----
        WB(2) COMPUTE(0, 0, 0) CBAR() ISSUE(2, 0)
        WB(2) COMPUTE(1, 1, 0) CBAR() ISSUE(3, 1)
        WB(2) COMPUTE(0, 2, 0) CBAR() ISSUE(4, 0)
        WB(2) COMPUTE(1, 3, 0) CBAR() ISSUE(5, 1)
        WB(2) COMPUTE(0, 4, 0) CBAR() ISSUE(6, 0)
        WB(2) COMPUTE(1, 5, 0) CBAR() ISSUE(7, 1)
        WB(2) COMPUTE(0, 6, 0) CBAR() ISSUE(8, 0)
        WB(3) COMPUTE(1, 7, 0) CBAR() ISSUE(9, 1)
        EPILOGUE(acc0, biasv0, 1, act0, d0, dumpo, creg0)
        // ---- group 1 (pinned Wh1 + streamed Wi2): chunks 8-15 ----
        WB2(5, 3) COMPUTE(0, 8, 1)  CBAR() ISSUE(10, 0)
        WB2(5, 3) COMPUTE(1, 9, 1)  CBAR() ISSUE(11, 1)
        WB(3)     COMPUTE(0, 10, 1) CBAR() ISSUE(12, 0)
        WB(3)     COMPUTE(1, 11, 1) CBAR() ISSUE(13, 1)
        WB(3)     COMPUTE(0, 12, 1) CBAR() ISSUE(14, 0)
        WB(3)     COMPUTE(1, 13, 1) CBAR() ISSUE(15, 1)
        WB(3)     COMPUTE(0, 14, 1) CBAR() ISSUE(16, 0)
        WB(3)     COMPUTE(1, 15, 1) CBAR() ISSUE(17, 1)
        EPILOGUE(acc1, biasv1, 0, act1, d1, dumpo, creg1)
        // ---- group 2 (streamed Wh2): chunks 16-23 ----
        WB2(5, 3) COMPUTE(0, 16, 2) CBAR() ISSUE(18, 0)
        WB2(5, 3) COMPUTE(1, 17, 2) CBAR() ISSUE(19, 1)
        WB(3)     COMPUTE(0, 18, 2) CBAR() ISSUE(20, 0)
        WB(3)     COMPUTE(1, 19, 2) CBAR() ISSUE(21, 1)
        WB(3)     COMPUTE(0, 20, 2) CBAR() ISSUE(22, 0)
        WB(3)     COMPUTE(1, 21, 2) CBAR() ISSUE(23, 1)
        WB(3)     COMPUTE(0, 22, 2) CBAR()
        WB(0)     COMPUTE(1, 23, 2) CBAR()
        EPILOGUE(acc2, biasv2, 0, act2, d2, ohp, creg2)

        // ---- block-wide drain, then grid barrier ----
        if (s < T_LEN + 1) {
            asm volatile("s_waitcnt vmcnt(0) lgkmcnt(0)" ::: "memory");
            __builtin_amdgcn_s_barrier();
            __builtin_amdgcn_sched_barrier(0);
            if (tid == 0) {
                __hip_atomic_fetch_add(&bar[barid], 1, __ATOMIC_RELEASE,
                                       __HIP_MEMORY_SCOPE_AGENT);
                while (__hip_atomic_load(&bar[barid], __ATOMIC_RELAXED,
                                         __HIP_MEMORY_SCOPE_AGENT) < (int)gridDim.x)
                    __builtin_amdgcn_s_sleep(8);
                __builtin_amdgcn_fence(__ATOMIC_ACQUIRE, "agent");
            }
            ++barid;
            __builtin_amdgcn_s_barrier();
            __builtin_amdgcn_sched_barrier(0);
        }
    }
#undef WB
#undef WB2
#undef CBAR
#undef ISSUE
#undef COMPUTE
#undef EPILOGUE
}

// ---------------------------------------------------------------------------
extern "C" void kernel_launch(void* const* d_in, const int* in_sizes, int n_in,
                              void* d_out, int out_size, void* d_ws, size_t ws_size,
                              hipStream_t stream) {
    (void)in_sizes; (void)n_in; (void)out_size; (void)ws_size;
    const int*   x   = (const int*)d_in[0];
    const float* h0  = (const float*)d_in[1];
    const float* c0  = (const float*)d_in[2];
    const float* emb = (const float*)d_in[3];
    const float* W[6] = { (const float*)d_in[4],  (const float*)d_in[6],
                          (const float*)d_in[8],  (const float*)d_in[10],
                          (const float*)d_in[12], (const float*)d_in[14] };
    const float* bi0 = (const float*)d_in[5];
    const float* bh0 = (const float*)d_in[7];
    const float* bi1 = (const float*)d_in[9];
    const float* bh1 = (const float*)d_in[11];
    const float* bi2 = (const float*)d_in[13];
    const float* bh2 = (const float*)d_in[15];
    const float* Wd  = (const float*)d_in[16];
    const float* bd  = (const float*)d_in[17];

    char* ws = (char*)d_ws;
    size_t off = 0;
    float* px0 = (float*)(ws + off); off += (size_t)TBROW * GDIM * 4;
    bf16* wsp0 = (bf16*)(ws + off); off += (size_t)GDIM * HDIM * 2;   // Wi0 hi
    bf16* wsp1 = (bf16*)(ws + off); off += (size_t)GDIM * HDIM * 2;   // Wi0 lo
    bf16* wdb  = (bf16*)(ws + off); off += (size_t)VOCAB * HDIM * 2;
    bf16* xeh  = (bf16*)(ws + off); off += (size_t)TBROW * HDIM * 2;
    bf16* xel  = (bf16*)(ws + off); off += (size_t)TBROW * HDIM * 2;
    bf16* outh = (bf16*)(ws + off); off += (size_t)TBROW * HDIM * 2;
    f16* w16[5];
    for (int i = 0; i < 5; ++i) { w16[i] = (f16*)(ws + off); off += (size_t)GDIM * HDIM * 2; }
    f16* hs16  = (f16*)(ws + off); off += (size_t)6 * BATCH * HDIM * 2;
    int* bar   = (int*)(ws + off); off += 1024;
    f16* dumph = (f16*)(ws + off); off += (size_t)BATCH * HDIM * 2;
    bf16* dumpo = (bf16*)(ws + off); off += (size_t)BATCH * HDIM * 2;

    // Wi0 split (for px0), Wd bf16, recurrence weights fp16
    split_kernel<<<1024, 256, 0, stream>>>(W[0], wsp0, wsp1, GDIM * HDIM / 4);
    conv_kernel<<<2048, 256, 0, stream>>>(Wd, wdb, VOCAB * HDIM / 4);
    for (int i = 0; i < 5; ++i)
        conv16_kernel<<<1024, 256, 0, stream>>>(W[i + 1], w16[i], GDIM * HDIM / 4);
    embed_kernel<<<TBROW, 256, 0, stream>>>(x, emb, xeh, xel);
    init16_kernel<<<768, 256, 0, stream>>>(h0, hs16);
    (void)hipMemsetAsync(bar, 0, 1024, stream);

    // px0 = xe @ Wi0^T + bi0 (split-3, fp32-accurate)
    dim3 gpx(GDIM / 128, TBROW / 128);
    gemm_bt<<<gpx, 256, 0, stream>>>(xeh, xel, xeh, wsp0, wsp0, wsp1,
                                     3, HDIM, bi0, px0, GDIM);

    // whole recurrence: fp16 wavefront, pinned-LDS weights for g0/g1
    lstm16<<<256, 512, 0, stream>>>(
        c0, w16[0], w16[1], w16[2], w16[3], w16[4],
        px0, bh0, bi1, bh1, bi2, bh2,
        hs16, outh, bar, dumph, dumpo);

    // decoder: d_out = outh @ Wd^T + bd
    dim3 gdec(VOCAB / 128, TBROW / 128);
    gemm_bt<<<gdec, 256, 0, stream>>>(outh, nullptr, nullptr, wdb, nullptr, nullptr,
                                      1, HDIM, bd, (float*)d_out, VOCAB);
}

// Round 16
// 2065.254 us; speedup vs baseline: 7.5131x; 1.0188x over previous
//
#include <hip/hip_runtime.h>

typedef __bf16 bf16;
typedef __bf16 bf16x8 __attribute__((ext_vector_type(8)));
typedef __bf16 bf16x4 __attribute__((ext_vector_type(4)));
typedef float  f32x4  __attribute__((ext_vector_type(4)));
typedef _Float16 f16;
typedef _Float16 f16x8 __attribute__((ext_vector_type(8)));
typedef _Float16 f16x4v __attribute__((ext_vector_type(4)));

#define T_LEN 70
#define BATCH 64
#define HDIM  1024
#define GDIM  4096
#define VOCAB 32000
#define TBROW (T_LEN * BATCH)   // 4480

#define MFMA16(a, b, c) __builtin_amdgcn_mfma_f32_16x16x32_bf16((a), (b), (c), 0, 0, 0)
#define MFMAH(a, b, c)  __builtin_amdgcn_mfma_f32_16x16x32_f16((a), (b), (c), 0, 0, 0)

typedef const __attribute__((address_space(1))) void gas_void;
typedef __attribute__((address_space(3))) void las_void;

// ---------------------------------------------------------------------------
__global__ void split_kernel(const float* __restrict__ w, bf16* __restrict__ hi,
                             bf16* __restrict__ lo, int n4) {
    int stride = gridDim.x * blockDim.x;
    for (int i = blockIdx.x * blockDim.x + threadIdx.x; i < n4; i += stride) {
        float4 v = reinterpret_cast<const float4*>(w)[i];
        bf16 h0 = (bf16)v.x, h1 = (bf16)v.y, h2 = (bf16)v.z, h3 = (bf16)v.w;
        bf16x4 hv = {h0, h1, h2, h3};
        bf16x4 lv = {(bf16)(v.x - (float)h0), (bf16)(v.y - (float)h1),
                     (bf16)(v.z - (float)h2), (bf16)(v.w - (float)h3)};
        reinterpret_cast<bf16x4*>(hi)[i] = hv;
        reinterpret_cast<bf16x4*>(lo)[i] = lv;
    }
}

__global__ void conv_kernel(const float* __restrict__ w, bf16* __restrict__ hi, int n4) {
    int stride = gridDim.x * blockDim.x;
    for (int i = blockIdx.x * blockDim.x + threadIdx.x; i < n4; i += stride) {
        float4 v = reinterpret_cast<const float4*>(w)[i];
        bf16x4 hv = {(bf16)v.x, (bf16)v.y, (bf16)v.z, (bf16)v.w};
        reinterpret_cast<bf16x4*>(hi)[i] = hv;
    }
}

__global__ void conv16_kernel(const float* __restrict__ w, f16* __restrict__ dst, int n4) {
    int stride = gridDim.x * blockDim.x;
    for (int i = blockIdx.x * blockDim.x + threadIdx.x; i < n4; i += stride) {
        float4 v = reinterpret_cast<const float4*>(w)[i];
        f16x4v h = {(f16)v.x, (f16)v.y, (f16)v.z, (f16)v.w};
        reinterpret_cast<f16x4v*>(dst)[i] = h;
    }
}

__global__ void embed_kernel(const int* __restrict__ x, const float* __restrict__ emb,
                             bf16* __restrict__ xh, bf16* __restrict__ xl) {
    int row = blockIdx.x;
    int tok = x[row];
    const float4* src = reinterpret_cast<const float4*>(emb + (size_t)tok * HDIM);
    bf16x4* dh = reinterpret_cast<bf16x4*>(xh + (size_t)row * HDIM);
    bf16x4* dl = reinterpret_cast<bf16x4*>(xl + (size_t)row * HDIM);
    for (int i = threadIdx.x; i < HDIM / 4; i += blockDim.x) {
        float4 v = src[i];
        bf16 h0 = (bf16)v.x, h1 = (bf16)v.y, h2 = (bf16)v.z, h3 = (bf16)v.w;
        dh[i] = (bf16x4){h0, h1, h2, h3};
        dl[i] = (bf16x4){(bf16)(v.x - (float)h0), (bf16)(v.y - (float)h1),
                         (bf16)(v.z - (float)h2), (bf16)(v.w - (float)h3)};
    }
}

// initial h (fp16) stored at parity 1 (first reads occur at input-parity 1)
__global__ void init16_kernel(const float* __restrict__ h0, f16* __restrict__ hs16) {
    int i = blockIdx.x * blockDim.x + threadIdx.x;
    int l = i >> 16, r = i & 65535;
    hs16[(size_t)(l * 2 + 1) * 65536 + r] = (f16)h0[i];
}

// ---------------------------------------------------------------------------
// GEMM C = sum_p A_p B_p^T + bias (unchanged)
// ---------------------------------------------------------------------------
__global__ __launch_bounds__(256) void gemm_bt(
    const bf16* __restrict__ a0, const bf16* __restrict__ a1, const bf16* __restrict__ a2,
    const bf16* __restrict__ b0, const bf16* __restrict__ b1, const bf16* __restrict__ b2,
    int npass, int K, const float* __restrict__ bias, float* __restrict__ C, int ldc) {
    __shared__ __align__(16) char As[128 * 128];
    __shared__ __align__(16) char Bs[128 * 128];
    const int tid = threadIdx.x;
    const int wid = tid >> 6, lane = tid & 63;
    const int l15 = lane & 15, l4 = lane >> 4;

    const int nbx = gridDim.x, mt = gridDim.y, nwg = nbx * mt;
    const int flat = blockIdx.y * nbx + blockIdx.x;
    const int xcd = flat & 7, o8 = flat >> 3;
    const int q8 = nwg >> 3, r8 = nwg & 7;
    const int wg = (xcd < r8 ? xcd * (q8 + 1) : r8 * (q8 + 1) + (xcd - r8) * q8) + o8;
    const int m0 = (wg % mt) * 128, n0 = (wg / mt) * 128;

    const int wr = (wid >> 1) * 64, wc = (wid & 1) * 64;
    const int swz_rd = (l15 & 7) << 4;
    const int rowL = lane >> 3;
    const int colE = (((lane & 7) ^ rowL)) << 3;

    f32x4 acc[4][4];
#pragma unroll
    for (int i = 0; i < 4; ++i)
#pragma unroll
        for (int j = 0; j < 4; ++j) acc[i][j] = (f32x4){0.f, 0.f, 0.f, 0.f};

    for (int p = 0; p < npass; ++p) {
        const bf16* A = (p == 0) ? a0 : ((p == 1) ? a1 : a2);
        const bf16* B = (p == 0) ? b0 : ((p == 1) ? b1 : b2);
        for (int k0 = 0; k0 < K; k0 += 64) {
            __syncthreads();
#pragma unroll
            for (int c2 = 0; c2 < 4; ++c2) {
                const int ch = wid * 4 + c2;
                const int row = ch * 8 + rowL;
                __builtin_amdgcn_global_load_lds(
                    (gas_void*)(A + (size_t)(m0 + row) * K + k0 + colE),
                    (las_void*)(As + ch * 1024), 16, 0, 0);
                __builtin_amdgcn_global_load_lds(
                    (gas_void*)(B + (size_t)(n0 + row) * K + k0 + colE),
                    (las_void*)(Bs + ch * 1024), 16, 0, 0);
            }
            __syncthreads();
#pragma unroll
            for (int ks = 0; ks < 2; ++ks) {
                const int cb = (ks * 64 + l4 * 16) ^ swz_rd;
                bf16x8 af[4], bfr[4];
#pragma unroll
                for (int mi = 0; mi < 4; ++mi)
                    af[mi] = *reinterpret_cast<const bf16x8*>(As + (wr + mi * 16 + l15) * 128 + cb);
#pragma unroll
                for (int ni = 0; ni < 4; ++ni)
                    bfr[ni] = *reinterpret_cast<const bf16x8*>(Bs + (wc + ni * 16 + l15) * 128 + cb);
#pragma unroll
                for (int mi = 0; mi < 4; ++mi)
#pragma unroll
                    for (int ni = 0; ni < 4; ++ni)
                        acc[mi][ni] = MFMA16(af[mi], bfr[ni], acc[mi][ni]);
            }
        }
    }
#pragma unroll
    for (int ni = 0; ni < 4; ++ni) {
        const int col = n0 + wc + ni * 16 + l15;
        const float bv = bias[col];
#pragma unroll
        for (int mi = 0; mi < 4; ++mi) {
            const int row0 = m0 + wr + mi * 16 + l4 * 4;
#pragma unroll
            for (int r = 0; r < 4; ++r)
                C[(size_t)(row0 + r) * ldc + col] = acc[mi][ni][r] + bv;
        }
    }
}

// ---------------------------------------------------------------------------
// Wavefront LSTM v12 = v11 with 3 stream bufs + ONE barrier per chunk.
// Slot i: WB(count); COMPUTE(buf i%3); ISSUE(chunk i+2 -> buf (i-1)%3, the
// buffer computed one barrier earlier — r7/r9-validated single-barrier
// pattern). No dup-B region (waves 4-7 load A only); asymmetric per-wave
// vmcnt via WB2 (FIFO-simulated incl. px loads + 2 epilogue stores on w<4).
// LDS: pinned 3x32768 | bufs 3x20480 @98304 (A 16K + B 4K) |
//      pex 4096 @159744 -> 163840 (= 160 KiB exactly).
// ---------------------------------------------------------------------------
__global__ __launch_bounds__(512, 1) void lstm16(
    const float* __restrict__ cin,
    const f16* __restrict__ W0, const f16* __restrict__ W1, const f16* __restrict__ W2,
    const f16* __restrict__ W3, const f16* __restrict__ W4,
    const float* __restrict__ px0,
    const float* __restrict__ bh0, const float* __restrict__ bi1,
    const float* __restrict__ bh1, const float* __restrict__ bi2,
    const float* __restrict__ bh2,
    f16* __restrict__ hs16, bf16* __restrict__ outh, int* __restrict__ bar,
    f16* __restrict__ dumph, bf16* __restrict__ dumpo) {
    __shared__ __align__(16) char smem[163840];

    const int tid = threadIdx.x;
    const int lane = tid & 63, w = tid >> 6;
    const int l15 = lane & 15, l4 = lane >> 4;
    const int wm = w & 3, wn = w >> 2;
    const int j0 = blockIdx.x * 4;
    const int lq = l15 >> 2;
    const int lcol = lq * 1024 + j0 + (l15 & 3);
    // staging lane geometry
    const int lr = lane >> 4;                  // 0..3
    const int lp = lane & 15;                  // 16B piece
    const int ar0 = w * 8 + lr, ar1 = w * 8 + 4 + lr;
    const size_t aoff0 = (size_t)ar0 * HDIM + (size_t)((lp ^ (ar0 & 15)) * 8);
    const size_t aoff1 = (size_t)ar1 * HDIM + (size_t)((lp ^ (ar1 & 15)) * 8);
    const int adst0 = w * 2048, adst1 = w * 2048 + 1024;
    // stream-B (waves 0-3 only): cr = w*4 + lr
    const int crS = (w & 3) * 4 + lr;
    const size_t boffS = (size_t)((crS >> 2) * 1024 + j0 + (crS & 3)) * HDIM +
                         (size_t)((lp ^ crS) * 8);
    const int bdstS = 16384 + (w & 3) * 1024;
    // fragment reads
    const int a_frow = (wm * 16 + l15) * 256;
    const int b_frow = l15 * 256;
    const int swz_r = l15 << 4;
    const int kbh = wn * 128;
    // gates
    const int gb = tid >> 2, gj = tid & 3;

    float biasv0 = 0.f, biasv1 = 0.f, biasv2 = 0.f;
    if (wn == 0) {
        biasv0 = bh0[lcol];
        biasv1 = bi1[lcol] + bh1[lcol];
        biasv2 = bi2[lcol] + bh2[lcol];
    }
    float creg0 = 0.f, creg1 = 0.f, creg2 = 0.f;
    if (tid < 256) {
        creg0 = cin[0 * 65536 + gb * 1024 + j0 + gj];
        creg1 = cin[1 * 65536 + gb * 1024 + j0 + gj];
        creg2 = cin[2 * 65536 + gb * 1024 + j0 + gj];
    }

    // ---- pin Wh0(W0), Wi1(W1), Wh1(W2) into LDS [0, 98304) ----
    {
        const f16* wp[3] = {W0, W1, W2};
#pragma unroll
        for (int it = 0; it < 12; ++it) {
            const int u = w * 12 + it;            // 0..95
            const int m = u >> 5, c = (u >> 2) & 7, q = u & 3;
            const int cr = q * 4 + lr;
            const size_t src = (size_t)((cr >> 2) * 1024 + j0 + (cr & 3)) * HDIM +
                               (size_t)(c * 128) + (size_t)((lp ^ cr) * 8);
            __builtin_amdgcn_global_load_lds(
                (gas_void*)(wp[m] + src),
                (las_void*)(smem + m * 32768 + c * 4096 + q * 1024), 16, 0, 0);
        }
    }
    asm volatile("s_waitcnt vmcnt(0) lgkmcnt(0)" ::: "memory");
    __syncthreads();

    auto hsp = [&](int l, int par) { return hs16 + (size_t)(l * 2 + par) * 65536; };

    int barid = 0;

#define WB(N)                                                                    \
    {                                                                            \
        asm volatile("s_waitcnt vmcnt(" #N ")" ::: "memory");                    \
        __builtin_amdgcn_s_barrier();                                            \
        __builtin_amdgcn_sched_barrier(0);                                       \
    }
#define WB2(N0, N1)                                                              \
    {                                                                            \
        if (w < 4) asm volatile("s_waitcnt vmcnt(" #N0 ")" ::: "memory");        \
        else       asm volatile("s_waitcnt vmcnt(" #N1 ")" ::: "memory");        \
        __builtin_amdgcn_s_barrier();                                            \
        __builtin_amdgcn_sched_barrier(0);                                       \
    }
#define CBAR()                                                                   \
    {                                                                            \
        asm volatile("s_waitcnt lgkmcnt(0)" ::: "memory");                       \
        __builtin_amdgcn_s_barrier();                                            \
        __builtin_amdgcn_sched_barrier(0);                                       \
    }

// buf = chunk % 3. A: 2 loads (all waves); stream-B (c>=8): waves 0-3 only.
#define ISSUE(c)                                                                 \
    {                                                                            \
        const int g_ = ((c) < 8) ? 0 : ((c) < 16) ? 1 : 2;                       \
        const f16* pa_ = (g_ == 0) ? A0 : (g_ == 1) ? A1 : A2;                   \
        const size_t k0_ = (size_t)(((c) & 7) * 128);                            \
        char* base_ = smem + 98304 + ((c) % 3) * 20480;                          \
        __builtin_amdgcn_global_load_lds((gas_void*)(pa_ + aoff0 + k0_),         \
                                         (las_void*)(base_ + adst0), 16, 0, 0);  \
        __builtin_amdgcn_global_load_lds((gas_void*)(pa_ + aoff1 + k0_),         \
                                         (las_void*)(base_ + adst1), 16, 0, 0);  \
        if ((c) >= 8 && w < 4) {                                                 \
            const f16* pb_ = ((c) < 16) ? W3 : W4;                               \
            __builtin_amdgcn_global_load_lds((gas_void*)(pb_ + boffS + k0_),     \
                                             (las_void*)(base_ + bdstS), 16, 0, 0); \
        }                                                                        \
    }

// G=0: acc0 += A*Wh0(pin0), acc1 += A*Wi1(pin1)
// G=1: acc1 += A*Wh1(pin2), acc2 += A*Wi2(stream)
// G=2: acc2 += A*Wh2(stream)
#define COMPUTE(buf, cc, G)                                                      \
    {                                                                            \
        const char* base_ = smem + 98304 + (buf) * 20480;                        \
        const char* pin_ = smem + ((G) == 0 ? 0 : 65536) + ((cc) & 7) * 4096;    \
        const char* pin1_ = smem + 32768 + ((cc) & 7) * 4096;                    \
        _Pragma("unroll") for (int ks_ = 0; ks_ < 2; ++ks_) {                    \
            const int kb_ = kbh + ks_ * 64 + l4 * 16;                            \
            const int co_ = kb_ ^ swz_r;                                         \
            f16x8 af_ = *reinterpret_cast<const f16x8*>(base_ + a_frow + co_);   \
            if ((G) == 0) {                                                      \
                f16x8 b0_ = *reinterpret_cast<const f16x8*>(pin_ + b_frow + co_);  \
                f16x8 b1_ = *reinterpret_cast<const f16x8*>(pin1_ + b_frow + co_); \
                if (act0) acc0 = MFMAH(af_, b0_, acc0);                          \
                if (act1) acc1 = MFMAH(af_, b1_, acc1);                          \
            } else if ((G) == 1) {                                               \
                f16x8 b0_ = *reinterpret_cast<const f16x8*>(pin_ + b_frow + co_);  \
                f16x8 b1_ = *reinterpret_cast<const f16x8*>(base_ + 16384 + b_frow + co_); \
                if (act1) acc1 = MFMAH(af_, b0_, acc1);                          \
                if (act2) acc2 = MFMAH(af_, b1_, acc2);                          \
            } else {                                                             \
                f16x8 b0_ = *reinterpret_cast<const f16x8*>(base_ + 16384 + b_frow + co_); \
                if (act2) acc2 = MFMAH(af_, b0_, acc2);                          \
            }                                                                    \
        }                                                                        \
    }

#define EPILOGUE(ACC, BIASV, USEPX, ACT, HD, OH, CREG)                           \
    {                                                                            \
        float* pex = reinterpret_cast<float*>(smem + 159744);                    \
        if (wn == 0) {                                                           \
            _Pragma("unroll") for (int r = 0; r < 4; ++r) {                      \
                const int row = wm * 16 + l4 * 4 + r;                            \
                float v = ACC[r] + (BIASV);                                      \
                if (USEPX) v += pxv[r];                                          \
                pex[row * 16 + l15] = v;                                         \
            }                                                                    \
        }                                                                        \
        CBAR();                                                                  \
        if (wn == 1) {                                                           \
            _Pragma("unroll") for (int r = 0; r < 4; ++r)                        \
                pex[(wm * 16 + l4 * 4 + r) * 16 + l15] += ACC[r];                \
        }                                                                        \
        CBAR();                                                                  \
        if (tid < 256) {                                                         \
            const float pi = pex[gb * 16 + 0 + gj];                              \
            const float pf = pex[gb * 16 + 4 + gj];                              \
            const float po = pex[gb * 16 + 8 + gj];                              \
            const float pg = pex[gb * 16 + 12 + gj];                             \
            const float ig = 1.f / (1.f + expf(-pi));                            \
            const float fg = 1.f / (1.f + expf(-pf));                            \
            const float og = 1.f / (1.f + expf(-po));                            \
            const float gg = tanhf(pg);                                          \
            const float c2v = fg * (CREG) + ig * gg;                             \
            const float h2v = og * tanhf(c2v);                                   \
            if (ACT) (CREG) = c2v;                                               \
            const int idx = gb * 1024 + j0 + gj;                                 \
            (HD)[idx] = (f16)h2v;                                                \
            (OH)[idx] = (bf16)h2v;                                               \
        }                                                                        \
    }

#pragma unroll 1
    for (int s = 0; s < T_LEN + 2; ++s) {
        const int ps = s & 1;
        const bool act0 = (s < T_LEN);
        const bool act1 = (s >= 1) && (s <= T_LEN);
        const bool act2 = (s >= 2);

        const f16* A0 = hsp(0, 1 - ps);
        const f16* A1 = hsp(1, ps);
        const f16* A2 = hsp(2, 1 - ps);
        f16* d0 = act0 ? hsp(0, ps)     : dumph;
        f16* d1 = act1 ? hsp(1, 1 - ps) : dumph;
        f16* d2 = act2 ? hsp(2, ps)     : dumph;
        bf16* ohp = act2 ? (outh + (size_t)(s - 2) * 65536) : dumpo;

        float pxv[4] = {0.f, 0.f, 0.f, 0.f};
        if (wn == 0 && act0) {
            const float* pxr = px0 + (size_t)s * (BATCH * GDIM) +
                               (size_t)(wm * 16 + l4 * 4) * GDIM + lcol;
#pragma unroll
            for (int r = 0; r < 4; ++r) pxv[r] = pxr[(size_t)r * GDIM];
        }

        f32x4 acc0 = (f32x4){0.f, 0.f, 0.f, 0.f};
        f32x4 acc1 = (f32x4){0.f, 0.f, 0.f, 0.f};
        f32x4 acc2 = (f32x4){0.f, 0.f, 0.f, 0.f};

        ISSUE(0) ISSUE(1) ISSUE(2)

        // ---- group 0 (pinned Wh0/Wi1): chunks 0-7 ----
        WB(4)     COMPUTE(0, 0, 0)
        WB(2)     COMPUTE(1, 1, 0) ISSUE(3)
        WB(2)     COMPUTE(2, 2, 0) ISSUE(4)
        WB(2)     COMPUTE(0, 3, 0) ISSUE(5)
        WB(2)     COMPUTE(1, 4, 0) ISSUE(6)
        WB(2)     COMPUTE(2, 5, 0) ISSUE(7)
        WB(2)     COMPUTE(0, 6, 0) ISSUE(8)
        WB2(3, 2) COMPUTE(1, 7, 0) ISSUE(9)
        EPILOGUE(acc0, biasv0, 1, act0, d0, dumpo, creg0)
        // ---- group 1 (pinned Wh1 + streamed Wi2): chunks 8-15 ----
        WB2(5, 2) COMPUTE(2, 8, 1)  ISSUE(10)
        WB2(5, 2) COMPUTE(0, 9, 1)  ISSUE(11)
        WB2(3, 2) COMPUTE(1, 10, 1) ISSUE(12)
        WB2(3, 2) COMPUTE(2, 11, 1) ISSUE(13)
        WB2(3, 2) COMPUTE(0, 12, 1) ISSUE(14)
        WB2(3, 2) COMPUTE(1, 13, 1) ISSUE(15)
        WB2(3, 2) COMPUTE(2, 14, 1) ISSUE(16)
        WB2(3, 2) COMPUTE(0, 15, 1) ISSUE(17)
        EPILOGUE(acc1, biasv1, 0, act1, d1, dumpo, creg1)
        // ---- group 2 (streamed Wh2): chunks 16-23 ----
        WB2(5, 2) COMPUTE(1, 16, 2) ISSUE(18)
        WB2(5, 2) COMPUTE(2, 17, 2) ISSUE(19)
        WB2(3, 2) COMPUTE(0, 18, 2) ISSUE(20)
        WB2(3, 2) COMPUTE(1, 19, 2) ISSUE(21)
        WB2(3, 2) COMPUTE(2, 20, 2) ISSUE(22)
        WB2(3, 2) COMPUTE(0, 21, 2) ISSUE(23)
        WB2(3, 2) COMPUTE(1, 22, 2)
        WB(0)     COMPUTE(2, 23, 2)
        EPILOGUE(acc2, biasv2, 0, act2, d2, ohp, creg2)

        // ---- block-wide drain, then grid barrier ----
        if (s < T_LEN + 1) {
            asm volatile("s_waitcnt vmcnt(0) lgkmcnt(0)" ::: "memory");
            __builtin_amdgcn_s_barrier();
            __builtin_amdgcn_sched_barrier(0);
            if (tid == 0) {
                __hip_atomic_fetch_add(&bar[barid], 1, __ATOMIC_RELEASE,
                                       __HIP_MEMORY_SCOPE_AGENT);
                while (__hip_atomic_load(&bar[barid], __ATOMIC_RELAXED,
                                         __HIP_MEMORY_SCOPE_AGENT) < (int)gridDim.x)
                    __builtin_amdgcn_s_sleep(8);
                __builtin_amdgcn_fence(__ATOMIC_ACQUIRE, "agent");
            }
            ++barid;
            __builtin_amdgcn_s_barrier();
            __builtin_amdgcn_sched_barrier(0);
        }
    }
#undef WB
#undef WB2
#undef CBAR
#undef ISSUE
#undef COMPUTE
#undef EPILOGUE
}

// ---------------------------------------------------------------------------
extern "C" void kernel_launch(void* const* d_in, const int* in_sizes, int n_in,
                              void* d_out, int out_size, void* d_ws, size_t ws_size,
                              hipStream_t stream) {
    (void)in_sizes; (void)n_in; (void)out_size; (void)ws_size;
    const int*   x   = (const int*)d_in[0];
    const float* h0  = (const float*)d_in[1];
    const float* c0  = (const float*)d_in[2];
    const float* emb = (const float*)d_in[3];
    const float* W[6] = { (const float*)d_in[4],  (const float*)d_in[6],
                          (const float*)d_in[8],  (const float*)d_in[10],
                          (const float*)d_in[12], (const float*)d_in[14] };
    const float* bi0 = (const float*)d_in[5];
    const float* bh0 = (const float*)d_in[7];
    const float* bi1 = (const float*)d_in[9];
    const float* bh1 = (const float*)d_in[11];
    const float* bi2 = (const float*)d_in[13];
    const float* bh2 = (const float*)d_in[15];
    const float* Wd  = (const float*)d_in[16];
    const float* bd  = (const float*)d_in[17];

    char* ws = (char*)d_ws;
    size_t off = 0;
    float* px0 = (float*)(ws + off); off += (size_t)TBROW * GDIM * 4;
    bf16* wsp0 = (bf16*)(ws + off); off += (size_t)GDIM * HDIM * 2;   // Wi0 hi
    bf16* wsp1 = (bf16*)(ws + off); off += (size_t)GDIM * HDIM * 2;   // Wi0 lo
    bf16* wdb  = (bf16*)(ws + off); off += (size_t)VOCAB * HDIM * 2;
    bf16* xeh  = (bf16*)(ws + off); off += (size_t)TBROW * HDIM * 2;
    bf16* xel  = (bf16*)(ws + off); off += (size_t)TBROW * HDIM * 2;
    bf16* outh = (bf16*)(ws + off); off += (size_t)TBROW * HDIM * 2;
    f16* w16[5];
    for (int i = 0; i < 5; ++i) { w16[i] = (f16*)(ws + off); off += (size_t)GDIM * HDIM * 2; }
    f16* hs16  = (f16*)(ws + off); off += (size_t)6 * BATCH * HDIM * 2;
    int* bar   = (int*)(ws + off); off += 1024;
    f16* dumph = (f16*)(ws + off); off += (size_t)BATCH * HDIM * 2;
    bf16* dumpo = (bf16*)(ws + off); off += (size_t)BATCH * HDIM * 2;

    // Wi0 split (for px0), Wd bf16, recurrence weights fp16
    split_kernel<<<1024, 256, 0, stream>>>(W[0], wsp0, wsp1, GDIM * HDIM / 4);
    conv_kernel<<<2048, 256, 0, stream>>>(Wd, wdb, VOCAB * HDIM / 4);
    for (int i = 0; i < 5; ++i)
        conv16_kernel<<<1024, 256, 0, stream>>>(W[i + 1], w16[i], GDIM * HDIM / 4);
    embed_kernel<<<TBROW, 256, 0, stream>>>(x, emb, xeh, xel);
    init16_kernel<<<768, 256, 0, stream>>>(h0, hs16);
    (void)hipMemsetAsync(bar, 0, 1024, stream);

    // px0 = xe @ Wi0^T + bi0 (split-3, fp32-accurate)
    dim3 gpx(GDIM / 128, TBROW / 128);
    gemm_bt<<<gpx, 256, 0, stream>>>(xeh, xel, xeh, wsp0, wsp0, wsp1,
                                     3, HDIM, bi0, px0, GDIM);

    // whole recurrence: fp16 wavefront, pinned-LDS g0/g1 weights, 1-barrier chunks
    lstm16<<<256, 512, 0, stream>>>(
        c0, w16[0], w16[1], w16[2], w16[3], w16[4],
        px0, bh0, bi1, bh1, bi2, bh2,
        hs16, outh, bar, dumph, dumpo);

    // decoder: d_out = outh @ Wd^T + bd
    dim3 gdec(VOCAB / 128, TBROW / 128);
    gemm_bt<<<gdec, 256, 0, stream>>>(outh, nullptr, nullptr, wdb, nullptr, nullptr,
                                      1, HDIM, bd, (float*)d_out, VOCAB);
}

// Round 17
// 1967.737 us; speedup vs baseline: 7.8854x; 1.0496x over previous
//
#include <hip/hip_runtime.h>

typedef __bf16 bf16;
typedef __bf16 bf16x8 __attribute__((ext_vector_type(8)));
typedef __bf16 bf16x4 __attribute__((ext_vector_type(4)));
typedef float  f32x4  __attribute__((ext_vector_type(4)));
typedef _Float16 f16;
typedef _Float16 f16x8 __attribute__((ext_vector_type(8)));
typedef _Float16 f16x4v __attribute__((ext_vector_type(4)));

#define T_LEN 70
#define BATCH 64
#define HDIM  1024
#define GDIM  4096
#define VOCAB 32000
#define TBROW (T_LEN * BATCH)   // 4480

#define MFMA16(a, b, c) __builtin_amdgcn_mfma_f32_16x16x32_bf16((a), (b), (c), 0, 0, 0)
#define MFMAH(a, b, c)  __builtin_amdgcn_mfma_f32_16x16x32_f16((a), (b), (c), 0, 0, 0)

typedef const __attribute__((address_space(1))) void gas_void;
typedef __attribute__((address_space(3))) void las_void;

// ---------------------------------------------------------------------------
__global__ void conv_kernel(const float* __restrict__ w, bf16* __restrict__ hi, int n4) {
    int stride = gridDim.x * blockDim.x;
    for (int i = blockIdx.x * blockDim.x + threadIdx.x; i < n4; i += stride) {
        float4 v = reinterpret_cast<const float4*>(w)[i];
        bf16x4 hv = {(bf16)v.x, (bf16)v.y, (bf16)v.z, (bf16)v.w};
        reinterpret_cast<bf16x4*>(hi)[i] = hv;
    }
}

// 6 weight matrices (4M floats each) -> contiguous fp16, one kernel
__global__ void conv16_multi(const float* __restrict__ s0, const float* __restrict__ s1,
                             const float* __restrict__ s2, const float* __restrict__ s3,
                             const float* __restrict__ s4, const float* __restrict__ s5,
                             f16* __restrict__ dst) {
    const int total = 6 * 1048576;   // float4 units
    int stride = gridDim.x * blockDim.x;
    for (int i = blockIdx.x * blockDim.x + threadIdx.x; i < total; i += stride) {
        const int m = i >> 20, r = i & 1048575;
        const float* s = (m == 0) ? s0 : (m == 1) ? s1 : (m == 2) ? s2
                       : (m == 3) ? s3 : (m == 4) ? s4 : s5;
        float4 v = reinterpret_cast<const float4*>(s)[r];
        f16x4v h = {(f16)v.x, (f16)v.y, (f16)v.z, (f16)v.w};
        reinterpret_cast<f16x4v*>(dst)[i] = h;
    }
}

// embedding gather -> fp16 xe
__global__ void embed16_kernel(const int* __restrict__ x, const float* __restrict__ emb,
                               f16* __restrict__ xe) {
    int row = blockIdx.x;
    int tok = x[row];
    const float4* src = reinterpret_cast<const float4*>(emb + (size_t)tok * HDIM);
    f16x4v* d = reinterpret_cast<f16x4v*>(xe + (size_t)row * HDIM);
    for (int i = threadIdx.x; i < HDIM / 4; i += blockDim.x) {
        float4 v = src[i];
        d[i] = (f16x4v){(f16)v.x, (f16)v.y, (f16)v.z, (f16)v.w};
    }
}

// initial h (fp16) stored at parity 1 (first reads occur at input-parity 1)
__global__ void init16_kernel(const float* __restrict__ h0, f16* __restrict__ hs16) {
    int i = blockIdx.x * blockDim.x + threadIdx.x;
    int l = i >> 16, r = i & 65535;
    hs16[(size_t)(l * 2 + 1) * 65536 + r] = (f16)h0[i];
}

// ---------------------------------------------------------------------------
// Decoder GEMM (bf16, single pass kept via npass arg) — unchanged from r16
// ---------------------------------------------------------------------------
__global__ __launch_bounds__(256) void gemm_bt(
    const bf16* __restrict__ a0, const bf16* __restrict__ a1, const bf16* __restrict__ a2,
    const bf16* __restrict__ b0, const bf16* __restrict__ b1, const bf16* __restrict__ b2,
    int npass, int K, const float* __restrict__ bias, float* __restrict__ C, int ldc) {
    __shared__ __align__(16) char As[128 * 128];
    __shared__ __align__(16) char Bs[128 * 128];
    const int tid = threadIdx.x;
    const int wid = tid >> 6, lane = tid & 63;
    const int l15 = lane & 15, l4 = lane >> 4;

    const int nbx = gridDim.x, mt = gridDim.y, nwg = nbx * mt;
    const int flat = blockIdx.y * nbx + blockIdx.x;
    const int xcd = flat & 7, o8 = flat >> 3;
    const int q8 = nwg >> 3, r8 = nwg & 7;
    const int wg = (xcd < r8 ? xcd * (q8 + 1) : r8 * (q8 + 1) + (xcd - r8) * q8) + o8;
    const int m0 = (wg % mt) * 128, n0 = (wg / mt) * 128;

    const int wr = (wid >> 1) * 64, wc = (wid & 1) * 64;
    const int swz_rd = (l15 & 7) << 4;
    const int rowL = lane >> 3;
    const int colE = (((lane & 7) ^ rowL)) << 3;

    f32x4 acc[4][4];
#pragma unroll
    for (int i = 0; i < 4; ++i)
#pragma unroll
        for (int j = 0; j < 4; ++j) acc[i][j] = (f32x4){0.f, 0.f, 0.f, 0.f};

    for (int p = 0; p < npass; ++p) {
        const bf16* A = (p == 0) ? a0 : ((p == 1) ? a1 : a2);
        const bf16* B = (p == 0) ? b0 : ((p == 1) ? b1 : b2);
        for (int k0 = 0; k0 < K; k0 += 64) {
            __syncthreads();
#pragma unroll
            for (int c2 = 0; c2 < 4; ++c2) {
                const int ch = wid * 4 + c2;
                const int row = ch * 8 + rowL;
                __builtin_amdgcn_global_load_lds(
                    (gas_void*)(A + (size_t)(m0 + row) * K + k0 + colE),
                    (las_void*)(As + ch * 1024), 16, 0, 0);
                __builtin_amdgcn_global_load_lds(
                    (gas_void*)(B + (size_t)(n0 + row) * K + k0 + colE),
                    (las_void*)(Bs + ch * 1024), 16, 0, 0);
            }
            __syncthreads();
#pragma unroll
            for (int ks = 0; ks < 2; ++ks) {
                const int cb = (ks * 64 + l4 * 16) ^ swz_rd;
                bf16x8 af[4], bfr[4];
#pragma unroll
                for (int mi = 0; mi < 4; ++mi)
                    af[mi] = *reinterpret_cast<const bf16x8*>(As + (wr + mi * 16 + l15) * 128 + cb);
#pragma unroll
                for (int ni = 0; ni < 4; ++ni)
                    bfr[ni] = *reinterpret_cast<const bf16x8*>(Bs + (wc + ni * 16 + l15) * 128 + cb);
#pragma unroll
                for (int mi = 0; mi < 4; ++mi)
#pragma unroll
                    for (int ni = 0; ni < 4; ++ni)
                        acc[mi][ni] = MFMA16(af[mi], bfr[ni], acc[mi][ni]);
            }
        }
    }
#pragma unroll
    for (int ni = 0; ni < 4; ++ni) {
        const int col = n0 + wc + ni * 16 + l15;
        const float bv = bias[col];
#pragma unroll
        for (int mi = 0; mi < 4; ++mi) {
            const int row0 = m0 + wr + mi * 16 + l4 * 4;
#pragma unroll
            for (int r = 0; r < 4; ++r)
                C[(size_t)(row0 + r) * ldc + col] = acc[mi][ni][r] + bv;
        }
    }
}

// ---------------------------------------------------------------------------
// px0 GEMM: fp16 single-pass clone of gemm_bt (identical byte addressing).
// C[M x N](f32) = A[M x K](f16) * B[N x K](f16)^T + bias[N]
// ---------------------------------------------------------------------------
__global__ __launch_bounds__(256) void gemm_f16(
    const f16* __restrict__ A, const f16* __restrict__ B,
    int K, const float* __restrict__ bias, float* __restrict__ C, int ldc) {
    __shared__ __align__(16) char As[128 * 128];
    __shared__ __align__(16) char Bs[128 * 128];
    const int tid = threadIdx.x;
    const int wid = tid >> 6, lane = tid & 63;
    const int l15 = lane & 15, l4 = lane >> 4;

    const int nbx = gridDim.x, mt = gridDim.y, nwg = nbx * mt;
    const int flat = blockIdx.y * nbx + blockIdx.x;
    const int xcd = flat & 7, o8 = flat >> 3;
    const int q8 = nwg >> 3, r8 = nwg & 7;
    const int wg = (xcd < r8 ? xcd * (q8 + 1) : r8 * (q8 + 1) + (xcd - r8) * q8) + o8;
    const int m0 = (wg % mt) * 128, n0 = (wg / mt) * 128;

    const int wr = (wid >> 1) * 64, wc = (wid & 1) * 64;
    const int swz_rd = (l15 & 7) << 4;
    const int rowL = lane >> 3;
    const int colE = (((lane & 7) ^ rowL)) << 3;

    f32x4 acc[4][4];
#pragma unroll
    for (int i = 0; i < 4; ++i)
#pragma unroll
        for (int j = 0; j < 4; ++j) acc[i][j] = (f32x4){0.f, 0.f, 0.f, 0.f};

    for (int k0 = 0; k0 < K; k0 += 64) {
        __syncthreads();
#pragma unroll
        for (int c2 = 0; c2 < 4; ++c2) {
            const int ch = wid * 4 + c2;
            const int row = ch * 8 + rowL;
            __builtin_amdgcn_global_load_lds(
                (gas_void*)(A + (size_t)(m0 + row) * K + k0 + colE),
                (las_void*)(As + ch * 1024), 16, 0, 0);
            __builtin_amdgcn_global_load_lds(
                (gas_void*)(B + (size_t)(n0 + row) * K + k0 + colE),
                (las_void*)(Bs + ch * 1024), 16, 0, 0);
        }
        __syncthreads();
#pragma unroll
        for (int ks = 0; ks < 2; ++ks) {
            const int cb = (ks * 64 + l4 * 16) ^ swz_rd;
            f16x8 af[4], bfr[4];
#pragma unroll
            for (int mi = 0; mi < 4; ++mi)
                af[mi] = *reinterpret_cast<const f16x8*>(As + (wr + mi * 16 + l15) * 128 + cb);
#pragma unroll
            for (int ni = 0; ni < 4; ++ni)
                bfr[ni] = *reinterpret_cast<const f16x8*>(Bs + (wc + ni * 16 + l15) * 128 + cb);
#pragma unroll
            for (int mi = 0; mi < 4; ++mi)
#pragma unroll
                for (int ni = 0; ni < 4; ++ni)
                    acc[mi][ni] = MFMAH(af[mi], bfr[ni], acc[mi][ni]);
        }
    }
#pragma unroll
    for (int ni = 0; ni < 4; ++ni) {
        const int col = n0 + wc + ni * 16 + l15;
        const float bv = bias[col];
#pragma unroll
        for (int mi = 0; mi < 4; ++mi) {
            const int row0 = m0 + wr + mi * 16 + l4 * 4;
#pragma unroll
            for (int r = 0; r < 4; ++r)
                C[(size_t)(row0 + r) * ldc + col] = acc[mi][ni][r] + bv;
        }
    }
}

// ---------------------------------------------------------------------------
// Wavefront LSTM v12 (unchanged from passing r16): fp16 single-pass, pinned
// LDS Wh0/Wi1/Wh1, 3 stream bufs, one barrier per chunk, asymmetric vmcnt.
// ---------------------------------------------------------------------------
__global__ __launch_bounds__(512, 1) void lstm16(
    const float* __restrict__ cin,
    const f16* __restrict__ W0, const f16* __restrict__ W1, const f16* __restrict__ W2,
    const f16* __restrict__ W3, const f16* __restrict__ W4,
    const float* __restrict__ px0,
    const float* __restrict__ bh0, const float* __restrict__ bi1,
    const float* __restrict__ bh1, const float* __restrict__ bi2,
    const float* __restrict__ bh2,
    f16* __restrict__ hs16, bf16* __restrict__ outh, int* __restrict__ bar,
    f16* __restrict__ dumph, bf16* __restrict__ dumpo) {
    __shared__ __align__(16) char smem[163840];

    const int tid = threadIdx.x;
    const int lane = tid & 63, w = tid >> 6;
    const int l15 = lane & 15, l4 = lane >> 4;
    const int wm = w & 3, wn = w >> 2;
    const int j0 = blockIdx.x * 4;
    const int lq = l15 >> 2;
    const int lcol = lq * 1024 + j0 + (l15 & 3);
    // staging lane geometry
    const int lr = lane >> 4;                  // 0..3
    const int lp = lane & 15;                  // 16B piece
    const int ar0 = w * 8 + lr, ar1 = w * 8 + 4 + lr;
    const size_t aoff0 = (size_t)ar0 * HDIM + (size_t)((lp ^ (ar0 & 15)) * 8);
    const size_t aoff1 = (size_t)ar1 * HDIM + (size_t)((lp ^ (ar1 & 15)) * 8);
    const int adst0 = w * 2048, adst1 = w * 2048 + 1024;
    // stream-B (waves 0-3 only): cr = w*4 + lr
    const int crS = (w & 3) * 4 + lr;
    const size_t boffS = (size_t)((crS >> 2) * 1024 + j0 + (crS & 3)) * HDIM +
                         (size_t)((lp ^ crS) * 8);
    const int bdstS = 16384 + (w & 3) * 1024;
    // fragment reads
    const int a_frow = (wm * 16 + l15) * 256;
    const int b_frow = l15 * 256;
    const int swz_r = l15 << 4;
    const int kbh = wn * 128;
    // gates
    const int gb = tid >> 2, gj = tid & 3;

    float biasv0 = 0.f, biasv1 = 0.f, biasv2 = 0.f;
    if (wn == 0) {
        biasv0 = bh0[lcol];
        biasv1 = bi1[lcol] + bh1[lcol];
        biasv2 = bi2[lcol] + bh2[lcol];
    }
    float creg0 = 0.f, creg1 = 0.f, creg2 = 0.f;
    if (tid < 256) {
        creg0 = cin[0 * 65536 + gb * 1024 + j0 + gj];
        creg1 = cin[1 * 65536 + gb * 1024 + j0 + gj];
        creg2 = cin[2 * 65536 + gb * 1024 + j0 + gj];
    }

    // ---- pin Wh0(W0), Wi1(W1), Wh1(W2) into LDS [0, 98304) ----
    {
        const f16* wp[3] = {W0, W1, W2};
#pragma unroll
        for (int it = 0; it < 12; ++it) {
            const int u = w * 12 + it;            // 0..95
            const int m = u >> 5, c = (u >> 2) & 7, q = u & 3;
            const int cr = q * 4 + lr;
            const size_t src = (size_t)((cr >> 2) * 1024 + j0 + (cr & 3)) * HDIM +
                               (size_t)(c * 128) + (size_t)((lp ^ cr) * 8);
            __builtin_amdgcn_global_load_lds(
                (gas_void*)(wp[m] + src),
                (las_void*)(smem + m * 32768 + c * 4096 + q * 1024), 16, 0, 0);
        }
    }
    asm volatile("s_waitcnt vmcnt(0) lgkmcnt(0)" ::: "memory");
    __syncthreads();

    auto hsp = [&](int l, int par) { return hs16 + (size_t)(l * 2 + par) * 65536; };

    int barid = 0;

#define WB(N)                                                                    \
    {                                                                            \
        asm volatile("s_waitcnt vmcnt(" #N ")" ::: "memory");                    \
        __builtin_amdgcn_s_barrier();                                            \
        __builtin_amdgcn_sched_barrier(0);                                       \
    }
#define WB2(N0, N1)                                                              \
    {                                                                            \
        if (w < 4) asm volatile("s_waitcnt vmcnt(" #N0 ")" ::: "memory");        \
        else       asm volatile("s_waitcnt vmcnt(" #N1 ")" ::: "memory");        \
        __builtin_amdgcn_s_barrier();                                            \
        __builtin_amdgcn_sched_barrier(0);                                       \
    }
#define CBAR()                                                                   \
    {                                                                            \
        asm volatile("s_waitcnt lgkmcnt(0)" ::: "memory");                       \
        __builtin_amdgcn_s_barrier();                                            \
        __builtin_amdgcn_sched_barrier(0);                                       \
    }

#define ISSUE(c)                                                                 \
    {                                                                            \
        const int g_ = ((c) < 8) ? 0 : ((c) < 16) ? 1 : 2;                       \
        const f16* pa_ = (g_ == 0) ? A0 : (g_ == 1) ? A1 : A2;                   \
        const size_t k0_ = (size_t)(((c) & 7) * 128);                            \
        char* base_ = smem + 98304 + ((c) % 3) * 20480;                          \
        __builtin_amdgcn_global_load_lds((gas_void*)(pa_ + aoff0 + k0_),         \
                                         (las_void*)(base_ + adst0), 16, 0, 0);  \
        __builtin_amdgcn_global_load_lds((gas_void*)(pa_ + aoff1 + k0_),         \
                                         (las_void*)(base_ + adst1), 16, 0, 0);  \
        if ((c) >= 8 && w < 4) {                                                 \
            const f16* pb_ = ((c) < 16) ? W3 : W4;                               \
            __builtin_amdgcn_global_load_lds((gas_void*)(pb_ + boffS + k0_),     \
                                             (las_void*)(base_ + bdstS), 16, 0, 0); \
        }                                                                        \
    }

#define COMPUTE(buf, cc, G)                                                      \
    {                                                                            \
        const char* base_ = smem + 98304 + (buf) * 20480;                        \
        const char* pin_ = smem + ((G) == 0 ? 0 : 65536) + ((cc) & 7) * 4096;    \
        const char* pin1_ = smem + 32768 + ((cc) & 7) * 4096;                    \
        _Pragma("unroll") for (int ks_ = 0; ks_ < 2; ++ks_) {                    \
            const int kb_ = kbh + ks_ * 64 + l4 * 16;                            \
            const int co_ = kb_ ^ swz_r;                                         \
            f16x8 af_ = *reinterpret_cast<const f16x8*>(base_ + a_frow + co_);   \
            if ((G) == 0) {                                                      \
                f16x8 b0_ = *reinterpret_cast<const f16x8*>(pin_ + b_frow + co_);  \
                f16x8 b1_ = *reinterpret_cast<const f16x8*>(pin1_ + b_frow + co_); \
                if (act0) acc0 = MFMAH(af_, b0_, acc0);                          \
                if (act1) acc1 = MFMAH(af_, b1_, acc1);                          \
            } else if ((G) == 1) {                                               \
                f16x8 b0_ = *reinterpret_cast<const f16x8*>(pin_ + b_frow + co_);  \
                f16x8 b1_ = *reinterpret_cast<const f16x8*>(base_ + 16384 + b_frow + co_); \
                if (act1) acc1 = MFMAH(af_, b0_, acc1);                          \
                if (act2) acc2 = MFMAH(af_, b1_, acc2);                          \
            } else {                                                             \
                f16x8 b0_ = *reinterpret_cast<const f16x8*>(base_ + 16384 + b_frow + co_); \
                if (act2) acc2 = MFMAH(af_, b0_, acc2);                          \
            }                                                                    \
        }                                                                        \
    }

#define EPILOGUE(ACC, BIASV, USEPX, ACT, HD, OH, CREG)                           \
    {                                                                            \
        float* pex = reinterpret_cast<float*>(smem + 159744);                    \
        if (wn == 0) {                                                           \
            _Pragma("unroll") for (int r = 0; r < 4; ++r) {                      \
                const int row = wm * 16 + l4 * 4 + r;                            \
                float v = ACC[r] + (BIASV);                                      \
                if (USEPX) v += pxv[r];                                          \
                pex[row * 16 + l15] = v;                                         \
            }                                                                    \
        }                                                                        \
        CBAR();                                                                  \
        if (wn == 1) {                                                           \
            _Pragma("unroll") for (int r = 0; r < 4; ++r)                        \
                pex[(wm * 16 + l4 * 4 + r) * 16 + l15] += ACC[r];                \
        }                                                                        \
        CBAR();                                                                  \
        if (tid < 256) {                                                         \
            const float pi = pex[gb * 16 + 0 + gj];                              \
            const float pf = pex[gb * 16 + 4 + gj];                              \
            const float po = pex[gb * 16 + 8 + gj];                              \
            const float pg = pex[gb * 16 + 12 + gj];                             \
            const float ig = 1.f / (1.f + expf(-pi));                            \
            const float fg = 1.f / (1.f + expf(-pf));                            \
            const float og = 1.f / (1.f + expf(-po));                            \
            const float gg = tanhf(pg);                                          \
            const float c2v = fg * (CREG) + ig * gg;                             \
            const float h2v = og * tanhf(c2v);                                   \
            if (ACT) (CREG) = c2v;                                               \
            const int idx = gb * 1024 + j0 + gj;                                 \
            (HD)[idx] = (f16)h2v;                                                \
            (OH)[idx] = (bf16)h2v;                                               \
        }                                                                        \
    }

#pragma unroll 1
    for (int s = 0; s < T_LEN + 2; ++s) {
        const int ps = s & 1;
        const bool act0 = (s < T_LEN);
        const bool act1 = (s >= 1) && (s <= T_LEN);
        const bool act2 = (s >= 2);

        const f16* A0 = hsp(0, 1 - ps);
        const f16* A1 = hsp(1, ps);
        const f16* A2 = hsp(2, 1 - ps);
        f16* d0 = act0 ? hsp(0, ps)     : dumph;
        f16* d1 = act1 ? hsp(1, 1 - ps) : dumph;
        f16* d2 = act2 ? hsp(2, ps)     : dumph;
        bf16* ohp = act2 ? (outh + (size_t)(s - 2) * 65536) : dumpo;

        float pxv[4] = {0.f, 0.f, 0.f, 0.f};
        if (wn == 0 && act0) {
            const float* pxr = px0 + (size_t)s * (BATCH * GDIM) +
                               (size_t)(wm * 16 + l4 * 4) * GDIM + lcol;
#pragma unroll
            for (int r = 0; r < 4; ++r) pxv[r] = pxr[(size_t)r * GDIM];
        }

        f32x4 acc0 = (f32x4){0.f, 0.f, 0.f, 0.f};
        f32x4 acc1 = (f32x4){0.f, 0.f, 0.f, 0.f};
        f32x4 acc2 = (f32x4){0.f, 0.f, 0.f, 0.f};

        ISSUE(0) ISSUE(1) ISSUE(2)

        // ---- group 0 (pinned Wh0/Wi1): chunks 0-7 ----
        WB(4)     COMPUTE(0, 0, 0)
        WB(2)     COMPUTE(1, 1, 0) ISSUE(3)
        WB(2)     COMPUTE(2, 2, 0) ISSUE(4)
        WB(2)     COMPUTE(0, 3, 0) ISSUE(5)
        WB(2)     COMPUTE(1, 4, 0) ISSUE(6)
        WB(2)     COMPUTE(2, 5, 0) ISSUE(7)
        WB(2)     COMPUTE(0, 6, 0) ISSUE(8)
        WB2(3, 2) COMPUTE(1, 7, 0) ISSUE(9)
        EPILOGUE(acc0, biasv0, 1, act0, d0, dumpo, creg0)
        // ---- group 1 (pinned Wh1 + streamed Wi2): chunks 8-15 ----
        WB2(5, 2) COMPUTE(2, 8, 1)  ISSUE(10)
        WB2(5, 2) COMPUTE(0, 9, 1)  ISSUE(11)
        WB2(3, 2) COMPUTE(1, 10, 1) ISSUE(12)
        WB2(3, 2) COMPUTE(2, 11, 1) ISSUE(13)
        WB2(3, 2) COMPUTE(0, 12, 1) ISSUE(14)
        WB2(3, 2) COMPUTE(1, 13, 1) ISSUE(15)
        WB2(3, 2) COMPUTE(2, 14, 1) ISSUE(16)
        WB2(3, 2) COMPUTE(0, 15, 1) ISSUE(17)
        EPILOGUE(acc1, biasv1, 0, act1, d1, dumpo, creg1)
        // ---- group 2 (streamed Wh2): chunks 16-23 ----
        WB2(5, 2) COMPUTE(1, 16, 2) ISSUE(18)
        WB2(5, 2) COMPUTE(2, 17, 2) ISSUE(19)
        WB2(3, 2) COMPUTE(0, 18, 2) ISSUE(20)
        WB2(3, 2) COMPUTE(1, 19, 2) ISSUE(21)
        WB2(3, 2) COMPUTE(2, 20, 2) ISSUE(22)
        WB2(3, 2) COMPUTE(0, 21, 2) ISSUE(23)
        WB2(3, 2) COMPUTE(1, 22, 2)
        WB(0)     COMPUTE(2, 23, 2)
        EPILOGUE(acc2, biasv2, 0, act2, d2, ohp, creg2)

        // ---- block-wide drain, then grid barrier ----
        if (s < T_LEN + 1) {
            asm volatile("s_waitcnt vmcnt(0) lgkmcnt(0)" ::: "memory");
            __builtin_amdgcn_s_barrier();
            __builtin_amdgcn_sched_barrier(0);
            if (tid == 0) {
                __hip_atomic_fetch_add(&bar[barid], 1, __ATOMIC_RELEASE,
                                       __HIP_MEMORY_SCOPE_AGENT);
                while (__hip_atomic_load(&bar[barid], __ATOMIC_RELAXED,
                                         __HIP_MEMORY_SCOPE_AGENT) < (int)gridDim.x)
                    __builtin_amdgcn_s_sleep(8);
                __builtin_amdgcn_fence(__ATOMIC_ACQUIRE, "agent");
            }
            ++barid;
            __builtin_amdgcn_s_barrier();
            __builtin_amdgcn_sched_barrier(0);
        }
    }
#undef WB
#undef WB2
#undef CBAR
#undef ISSUE
#undef COMPUTE
#undef EPILOGUE
}

// ---------------------------------------------------------------------------
extern "C" void kernel_launch(void* const* d_in, const int* in_sizes, int n_in,
                              void* d_out, int out_size, void* d_ws, size_t ws_size,
                              hipStream_t stream) {
    (void)in_sizes; (void)n_in; (void)out_size; (void)ws_size;
    const int*   x   = (const int*)d_in[0];
    const float* h0  = (const float*)d_in[1];
    const float* c0  = (const float*)d_in[2];
    const float* emb = (const float*)d_in[3];
    const float* W[6] = { (const float*)d_in[4],  (const float*)d_in[6],
                          (const float*)d_in[8],  (const float*)d_in[10],
                          (const float*)d_in[12], (const float*)d_in[14] };
    const float* bi0 = (const float*)d_in[5];
    const float* bh0 = (const float*)d_in[7];
    const float* bi1 = (const float*)d_in[9];
    const float* bh1 = (const float*)d_in[11];
    const float* bi2 = (const float*)d_in[13];
    const float* bh2 = (const float*)d_in[15];
    const float* Wd  = (const float*)d_in[16];
    const float* bd  = (const float*)d_in[17];

    char* ws = (char*)d_ws;
    size_t off = 0;
    float* px0 = (float*)(ws + off); off += (size_t)TBROW * GDIM * 4;
    bf16* wdb  = (bf16*)(ws + off); off += (size_t)VOCAB * HDIM * 2;
    f16* xe16  = (f16*)(ws + off);  off += (size_t)TBROW * HDIM * 2;
    bf16* outh = (bf16*)(ws + off); off += (size_t)TBROW * HDIM * 2;
    f16* w16   = (f16*)(ws + off);  off += (size_t)6 * GDIM * HDIM * 2;  // Wi0,Wh0,Wi1,Wh1,Wi2,Wh2
    f16* hs16  = (f16*)(ws + off);  off += (size_t)6 * BATCH * HDIM * 2;
    int* bar   = (int*)(ws + off);  off += 1024;
    f16* dumph = (f16*)(ws + off);  off += (size_t)BATCH * HDIM * 2;
    bf16* dumpo = (bf16*)(ws + off); off += (size_t)BATCH * HDIM * 2;
    const size_t WSTRIDE = (size_t)GDIM * HDIM;   // 4194304 elements

    conv_kernel<<<2048, 256, 0, stream>>>(Wd, wdb, VOCAB * HDIM / 4);
    conv16_multi<<<3072, 256, 0, stream>>>(W[0], W[1], W[2], W[3], W[4], W[5], w16);
    embed16_kernel<<<TBROW, 256, 0, stream>>>(x, emb, xe16);
    init16_kernel<<<768, 256, 0, stream>>>(h0, hs16);
    (void)hipMemsetAsync(bar, 0, 1024, stream);

    // px0 = xe @ Wi0^T + bi0 (fp16 single pass)
    dim3 gpx(GDIM / 128, TBROW / 128);
    gemm_f16<<<gpx, 256, 0, stream>>>(xe16, w16 + 0 * WSTRIDE, HDIM, bi0, px0, GDIM);

    // whole recurrence: fp16 wavefront, pinned-LDS g0/g1 weights, 1-barrier chunks
    lstm16<<<256, 512, 0, stream>>>(
        c0,
        w16 + 1 * WSTRIDE,        // Wh0
        w16 + 2 * WSTRIDE,        // Wi1
        w16 + 3 * WSTRIDE,        // Wh1
        w16 + 4 * WSTRIDE,        // Wi2
        w16 + 5 * WSTRIDE,        // Wh2
        px0, bh0, bi1, bh1, bi2, bh2,
        hs16, outh, bar, dumph, dumpo);

    // decoder: d_out = outh @ Wd^T + bd (bf16 single pass)
    dim3 gdec(VOCAB / 128, TBROW / 128);
    gemm_bt<<<gdec, 256, 0, stream>>>(outh, nullptr, nullptr, wdb, nullptr, nullptr,
                                      1, HDIM, bd, (float*)d_out, VOCAB);
}